// Round 17
// baseline (169.534 us; speedup 1.0000x reference)
//
#include <hip/hip_runtime.h>

#define HID 128
#define DNODE 64
#define NNODES 50000
#define NEDGES 600000
#define NGRAPHS 64
#define LN_EPS 1e-5f

#define NBUCK 782                 // buckets of 64 nodes: dst>>6, max 49999>>6=781
#define EPB 4096                  // edges per K1 block
#define BK1 ((NEDGES + EPB - 1) / EPB)   // 147

#define NZERO (NBUCK + 1 + NGRAPHS * HID)  // gcount+donecnt+sums = 8975 ints
#define NZERO4 ((NZERO + 3) / 4)           // 2244 (1 int spills into boff[0], rewritten)
#define Z_BLKS ((NZERO4 + 255) / 256)      // 9
#define PKWC_BLKS (3 * 16384 / 256)        // 192
#define PKWE_BLKS (8192 / 256)             // 32
#define BND_BLKS ((NNODES + 255) / 256)    // 196

#define ENC_BLKS ((NNODES + 63) / 64)      // 782
#define E256_BLKS ((NEDGES + 255) / 256)   // 2344

#define GC_BLKS (NNODES / 16)              // 3125 (exact)

typedef __attribute__((ext_vector_type(8))) short bf16x8;
typedef __attribute__((ext_vector_type(8))) unsigned short u16x8;
typedef __attribute__((ext_vector_type(4))) float f32x4;
typedef __attribute__((ext_vector_type(2))) float f32x2;

static __device__ __forceinline__ unsigned short f2bf(float f) {
  unsigned int u = __float_as_uint(f);
  u += 0x7fffu + ((u >> 16) & 1u);   // RNE
  return (unsigned short)(u >> 16);
}
static __device__ __forceinline__ float bf2f(unsigned short h) {
  return __uint_as_float(((unsigned int)h) << 16);
}
static __device__ __forceinline__ void fp8x4_to_f32(unsigned int w, float* o) {
  f32x2 lo = __builtin_amdgcn_cvt_pk_f32_fp8(w, false);
  f32x2 hi = __builtin_amdgcn_cvt_pk_f32_fp8(w, true);
  o[0] = lo[0]; o[1] = lo[1]; o[2] = hi[0]; o[3] = hi[1];
}
static __device__ __forceinline__ unsigned int f32x4_to_fp8(float a, float b,
                                                            float c, float d) {
  unsigned int v = __builtin_amdgcn_cvt_pk_fp8_f32(a, b, 0, false);
  v = __builtin_amdgcn_cvt_pk_fp8_f32(c, d, v, true);
  return v;
}

// ======== prep0: zero gcount+donecnt+sums | pack conv W | pack enc W | bounds
__global__ void __launch_bounds__(256) prep0_kernel(
    int4* __restrict__ zp, const float* __restrict__ W,
    unsigned short* __restrict__ Wp, const float* __restrict__ enc_w,
    unsigned short* __restrict__ Wpe, const int* __restrict__ batch,
    int* __restrict__ gstart, int* __restrict__ gend, int* __restrict__ off) {
  int b = blockIdx.x;
  if (b == 0 && threadIdx.x == 0) off[NNODES] = NEDGES;
  if (b < Z_BLKS) {
    int i = b * 256 + threadIdx.x;
    if (i < NZERO4) zp[i] = make_int4(0, 0, 0, 0);
  } else if (b < Z_BLKS + PKWC_BLKS) {
    int t = (b - Z_BLKS) * 256 + threadIdx.x;
    int i = t & 7;
    int lane = (t >> 3) & 63;
    int kk = (t >> 9) & 3;
    int nt = (t >> 11) & 7;
    int layer = t >> 14;
    int k = kk * 32 + (lane >> 4) * 8 + i;
    int n = nt * 16 + (lane & 15);
    Wp[t] = f2bf(W[((size_t)layer * HID + k) * HID + n]);
  } else if (b < Z_BLKS + PKWC_BLKS + PKWE_BLKS) {
    int t = (b - Z_BLKS - PKWC_BLKS) * 256 + threadIdx.x;
    int i = t & 7;
    int lane = (t >> 3) & 63;
    int kk = (t >> 9) & 1;
    int nt = (t >> 10) & 7;
    int k = kk * 32 + (lane >> 4) * 8 + i;
    int n = nt * 16 + (lane & 15);
    Wpe[t] = f2bf(enc_w[(size_t)k * HID + n]);
  } else {
    int i = (b - Z_BLKS - PKWC_BLKS - PKWE_BLKS) * 256 + threadIdx.x;
    if (i < NNODES) {
      int g = batch[i];
      if (i == 0 || batch[i - 1] != g) gstart[g] = i;
      if (i == NNODES - 1 || batch[i + 1] != g) gend[g] = i + 1;
    }
  }
}

// ======== prep1: K1 bucket-count + last-block boff scan | encoder+conv0 ====
__global__ void __launch_bounds__(256) prep1_kernel(
    const float* __restrict__ x, const unsigned short* __restrict__ Wpe,
    const unsigned short* __restrict__ Wp0, const float* __restrict__ enc_b,
    const float* __restrict__ ln_g, const float* __restrict__ ln_b,
    unsigned char* __restrict__ B1, const int* __restrict__ dst,
    int* __restrict__ gcount, unsigned int* __restrict__ bpos,
    int* __restrict__ donecnt, int* __restrict__ boff) {
  __shared__ __align__(16) unsigned short tile[4][16][136];
  __shared__ int lhist[NBUCK];
  __shared__ int tsum[256];
  __shared__ int lastf;
  int blk = blockIdx.x;
  if (blk < BK1) {
    int t = threadIdx.x;
    for (int i = t; i < NBUCK; i += 256) lhist[i] = 0;
    __syncthreads();
    int base = blk * EPB;
    int myd[16];
    int myr[16];
#pragma unroll
    for (int i = 0; i < 16; ++i) {
      int e = base + i * 256 + t;
      if (e < NEDGES) {
        int d = dst[e];
        myd[i] = d;
        myr[i] = atomicAdd(&lhist[d >> 6], 1);
      } else {
        myd[i] = -1;
        myr[i] = 0;
      }
    }
    __syncthreads();
    for (int i = t; i < NBUCK; i += 256) {
      int c = lhist[i];
      if (c) lhist[i] = atomicAdd(&gcount[i], c);   // block's base within bucket
    }
    __syncthreads();
#pragma unroll
    for (int i = 0; i < 16; ++i) {
      if (myd[i] >= 0) {
        int e = base + i * 256 + t;
        bpos[e] = (unsigned int)(lhist[myd[i] >> 6] + myr[i]);
      }
    }
    // ---- decoupled epilogue: last-finishing block materializes boff ----
    __threadfence();
    __syncthreads();
    if (t == 0) lastf = (atomicAdd(donecnt, 1) == BK1 - 1) ? 1 : 0;
    __syncthreads();
    if (lastf) {
      int g[4];
      int s = 0;
#pragma unroll
      for (int i = 0; i < 4; ++i) {
        int idx = 4 * t + i;
        g[i] = (idx < NBUCK) ? atomicAdd(&gcount[idx], 0) : 0;  // coherent read
        s += g[i];
      }
      tsum[t] = s;
      __syncthreads();
      for (int d = 1; d < 256; d <<= 1) {
        int v = (t >= d) ? tsum[t - d] : 0;
        __syncthreads();
        tsum[t] += v;
        __syncthreads();
      }
      int run = tsum[t] - s;   // exclusive base for this thread's 4 buckets
#pragma unroll
      for (int i = 0; i < 4; ++i) {
        int idx = 4 * t + i;
        if (idx < NBUCK) boff[idx] = run;
        run += g[i];
      }
      if (t == 255) boff[NBUCK] = run;   // = NEDGES
    }
    return;
  }
  int b2 = blk - BK1;
  int wave = threadIdx.x >> 6;
  int lane = threadIdx.x & 63;
  int l15 = lane & 15, h = lane >> 4;
  int base = b2 * 64 + wave * 16;
  int row = base + l15;
  int rowc = row < NNODES ? row : NNODES - 1;
  const float* xr = x + (size_t)rowc * DNODE;
  bf16x8 a[2];
#pragma unroll
  for (int kk = 0; kk < 2; ++kk) {
    float4 p0 = *(const float4*)(xr + kk * 32 + h * 8);
    float4 p1 = *(const float4*)(xr + kk * 32 + h * 8 + 4);
    a[kk][0] = (short)f2bf(p0.x); a[kk][1] = (short)f2bf(p0.y);
    a[kk][2] = (short)f2bf(p0.z); a[kk][3] = (short)f2bf(p0.w);
    a[kk][4] = (short)f2bf(p1.x); a[kk][5] = (short)f2bf(p1.y);
    a[kk][6] = (short)f2bf(p1.z); a[kk][7] = (short)f2bf(p1.w);
  }
  f32x4 acc[8];
#pragma unroll
  for (int nt = 0; nt < 8; ++nt) acc[nt] = (f32x4)(0.f);
  const bf16x8* wp = (const bf16x8*)Wpe;
#pragma unroll
  for (int kk = 0; kk < 2; ++kk)
#pragma unroll
    for (int nt = 0; nt < 8; ++nt)
      acc[nt] = __builtin_amdgcn_mfma_f32_16x16x32_bf16(a[kk], wp[(nt * 2 + kk) * 64 + lane],
                                                        acc[nt], 0, 0, 0);
  float s[4] = {0.f, 0.f, 0.f, 0.f}, s2[4] = {0.f, 0.f, 0.f, 0.f};
#pragma unroll
  for (int nt = 0; nt < 8; ++nt) {
    float bcol = enc_b[nt * 16 + l15];
#pragma unroll
    for (int r = 0; r < 4; ++r) {
      float v = fmaxf(acc[nt][r] + bcol, 0.f);
      acc[nt][r] = v;
      s[r] += v;
      s2[r] = fmaf(v, v, s2[r]);
    }
  }
#pragma unroll
  for (int r = 0; r < 4; ++r) {
#pragma unroll
    for (int o = 1; o < 16; o <<= 1) {
      s[r] += __shfl_xor(s[r], o);
      s2[r] += __shfl_xor(s2[r], o);
    }
  }
  float mu[4], rstd[4];
#pragma unroll
  for (int r = 0; r < 4; ++r) {
    mu[r] = s[r] * (1.0f / HID);
    float var = s2[r] * (1.0f / HID) - mu[r] * mu[r];
    rstd[r] = rsqrtf(var + LN_EPS);
  }
#pragma unroll
  for (int nt = 0; nt < 8; ++nt) {
    float gcol = ln_g[nt * 16 + l15], bbcol = ln_b[nt * 16 + l15];
#pragma unroll
    for (int r = 0; r < 4; ++r)
      tile[wave][h * 4 + r][nt * 16 + l15] =
          f2bf((acc[nt][r] - mu[r]) * rstd[r] * gcol + bbcol);
  }
  __syncthreads();
  // ---- fused conv0 ----
  bf16x8 a2[4];
#pragma unroll
  for (int kk = 0; kk < 4; ++kk)
    a2[kk] = *(const bf16x8*)&tile[wave][l15][kk * 32 + h * 8];
  __syncthreads();
  f32x4 acc2[8];
#pragma unroll
  for (int nt = 0; nt < 8; ++nt) acc2[nt] = (f32x4)(0.f);
#pragma unroll
  for (int kk = 0; kk < 4; ++kk) {
#pragma unroll
    for (int nt = 0; nt < 8; ++nt) {
      bf16x8 wf = *(const bf16x8*)(Wp0 + (((nt * 4 + kk) * 64 + lane) << 3));
      acc2[nt] = __builtin_amdgcn_mfma_f32_16x16x32_bf16(a2[kk], wf, acc2[nt], 0, 0, 0);
    }
  }
#pragma unroll
  for (int nt = 0; nt < 8; ++nt)
#pragma unroll
    for (int r = 0; r < 4; ++r)
      tile[wave][h * 4 + r][nt * 16 + l15] = f2bf(acc2[nt][r]);
  __syncthreads();
  int trow = lane >> 2, tseg = lane & 3;
  int orow = base + trow;
  if (orow < NNODES) {
#pragma unroll
    for (int q = 0; q < 4; ++q) {
      u16x8 v = *(const u16x8*)&tile[wave][trow][tseg * 32 + q * 8];
      uint2 o;
      o.x = f32x4_to_fp8(bf2f((unsigned short)v[0]), bf2f((unsigned short)v[1]),
                         bf2f((unsigned short)v[2]), bf2f((unsigned short)v[3]));
      o.y = f32x4_to_fp8(bf2f((unsigned short)v[4]), bf2f((unsigned short)v[5]),
                         bf2f((unsigned short)v[6]), bf2f((unsigned short)v[7]));
      *(uint2*)(B1 + (size_t)orow * HID + tseg * 32 + q * 8) = o;
    }
  }
}

// ======== scat: direct boff scatter ========
__global__ void __launch_bounds__(256) scat_kernel(
    const int* __restrict__ src, const int* __restrict__ dst,
    const unsigned int* __restrict__ bpos, const int* __restrict__ boff,
    unsigned int* __restrict__ sorted1) {
  int e = blockIdx.x * 256 + threadIdx.x;
  if (e >= NEDGES) return;
  int d = dst[e];
  sorted1[boff[d >> 6] + bpos[e]] =
      ((unsigned int)d << 16) | (unsigned int)src[e];
}

// ======== bucketA: hist64 -> off/dis (base from boff) ========
__global__ void __launch_bounds__(256) bucketA_kernel(
    const int* __restrict__ boff, const unsigned int* __restrict__ sorted1,
    int* __restrict__ off, float* __restrict__ dis) {
  __shared__ int h64[64];
  int b = blockIdx.x, t = threadIdx.x;
  int base = boff[b];
  int end = boff[b + 1];
  if (t < 64) h64[t] = 0;
  __syncthreads();
  for (int i = base + t; i < end; i += 256)
    atomicAdd(&h64[(sorted1[i] >> 16) & 63], 1);
  __syncthreads();
  if (t < 64) {   // threads 0..63 are wave 0 (wave64)
    int own = h64[t];
    int x = own;
#pragma unroll
    for (int o = 1; o < 64; o <<= 1) {
      int v = __shfl_up(x, o);
      if (t >= o) x += v;
    }
    int n = b * 64 + t;
    if (n < NNODES) {
      off[n] = base + (x - own);
      dis[n] = rsqrtf((float)own + 1.0f);
    }
  }
}

// ======== bucketB: compact + norm fused -> final epack ========
__global__ void __launch_bounds__(256) bucketB_kernel(
    const int* __restrict__ boff, const int* __restrict__ off,
    const float* __restrict__ dis, const unsigned int* __restrict__ sorted1,
    unsigned int* __restrict__ epack) {
  __shared__ int cur[64];
  __shared__ float disl[64];
  int b = blockIdx.x, t = threadIdx.x;
  if (t < 64) {
    int n = b * 64 + t;
    cur[t] = (n < NNODES) ? off[n] : NEDGES;
    disl[t] = (n < NNODES) ? dis[n] : 1.0f;
  }
  __syncthreads();
  int base = boff[b];
  int end = boff[b + 1];
  for (int i = base + t; i < end; i += 256) {
    unsigned int u = sorted1[i];
    int d63 = (u >> 16) & 63;
    int sN = u & 0xFFFFu;
    int p = atomicAdd(&cur[d63], 1);
    float wgt = dis[sN] * disl[d63];
    epack[p] = ((unsigned int)f2bf(wgt) << 16) | (unsigned int)sN;
  }
}

// ======== gc: gather(layer L, fp8 rows) fused with conv(layer L+1) ========
__global__ void __launch_bounds__(1024) gc_kernel(
    const int* __restrict__ off, const unsigned int* __restrict__ epack,
    const float* __restrict__ dis, const float* __restrict__ bias,
    const unsigned char* __restrict__ Bin, const unsigned short* __restrict__ Wnext,
    unsigned char* __restrict__ Bout) {
  __shared__ __align__(16) unsigned short As[16][136];
  __shared__ __align__(16) unsigned short Bs[16][136];
  int w = threadIdx.x >> 6, lane = threadIdx.x & 63;
  int n = blockIdx.x * 16 + w;
  int slot = lane >> 4, p = lane & 15;
  int lo = off[n], hi = off[n + 1];
  float acc0[8], acc1[8];
#pragma unroll
  for (int i = 0; i < 8; ++i) { acc0[i] = 0.f; acc1[i] = 0.f; }
  int idx = lo + slot;
  for (; idx + 4 < hi; idx += 8) {
    unsigned int e0 = epack[idx];
    unsigned int e1 = epack[idx + 4];
    float w0 = bf2f((unsigned short)(e0 >> 16));
    float w1 = bf2f((unsigned short)(e1 >> 16));
    uint2 v0 = *(const uint2*)(Bin + (size_t)(e0 & 0xFFFFu) * HID + p * 8);
    uint2 v1 = *(const uint2*)(Bin + (size_t)(e1 & 0xFFFFu) * HID + p * 8);
    float f0[8], f1[8];
    fp8x4_to_f32(v0.x, f0); fp8x4_to_f32(v0.y, f0 + 4);
    fp8x4_to_f32(v1.x, f1); fp8x4_to_f32(v1.y, f1 + 4);
#pragma unroll
    for (int i = 0; i < 8; ++i) acc0[i] = fmaf(f0[i], w0, acc0[i]);
#pragma unroll
    for (int i = 0; i < 8; ++i) acc1[i] = fmaf(f1[i], w1, acc1[i]);
  }
  if (idx < hi) {
    unsigned int e0 = epack[idx];
    float w0 = bf2f((unsigned short)(e0 >> 16));
    uint2 v0 = *(const uint2*)(Bin + (size_t)(e0 & 0xFFFFu) * HID + p * 8);
    float f0[8];
    fp8x4_to_f32(v0.x, f0); fp8x4_to_f32(v0.y, f0 + 4);
#pragma unroll
    for (int i = 0; i < 8; ++i) acc0[i] = fmaf(f0[i], w0, acc0[i]);
  }
#pragma unroll
  for (int i = 0; i < 8; ++i) {
    float a = acc0[i] + acc1[i];
    a += __shfl_xor(a, 16);
    a += __shfl_xor(a, 32);
    acc0[i] = a;
  }
  if (slot == 0) {
    float dn = dis[n];
    float d2 = dn * dn;
    uint2 sv = *(const uint2*)(Bin + (size_t)n * HID + p * 8);
    float sf[8];
    fp8x4_to_f32(sv.x, sf); fp8x4_to_f32(sv.y, sf + 4);
    float4 b0 = ((const float4*)bias)[p * 2];
    float4 b1 = ((const float4*)bias)[p * 2 + 1];
    float bb[8] = {b0.x, b0.y, b0.z, b0.w, b1.x, b1.y, b1.z, b1.w};
    u16x8 o;
#pragma unroll
    for (int i = 0; i < 8; ++i) {
      float v = fmaxf(fmaf(sf[i], d2, bb[i]) + acc0[i], 0.f);
      o[i] = (short)f2bf(v);
    }
    *(u16x8*)&As[w][p * 8] = o;
  }
  __syncthreads();
  if (w < 8) {
    bf16x8 a[4];
#pragma unroll
    for (int kk = 0; kk < 4; ++kk)
      a[kk] = *(const bf16x8*)&As[p][kk * 32 + slot * 8];
    f32x4 acc = (f32x4)(0.f);
#pragma unroll
    for (int kk = 0; kk < 4; ++kk) {
      bf16x8 wf = *(const bf16x8*)(Wnext + (((w * 4 + kk) * 64 + lane) << 3));
      acc = __builtin_amdgcn_mfma_f32_16x16x32_bf16(a[kk], wf, acc, 0, 0, 0);
    }
#pragma unroll
    for (int r = 0; r < 4; ++r)
      Bs[slot * 4 + r][w * 16 + p] = f2bf(acc[r]);
  }
  __syncthreads();
  if (threadIdx.x < 256) {
    int row = threadIdx.x >> 4, seg = threadIdx.x & 15;
    u16x8 v = *(const u16x8*)&Bs[row][seg * 8];
    uint2 o;
    o.x = f32x4_to_fp8(bf2f((unsigned short)v[0]), bf2f((unsigned short)v[1]),
                       bf2f((unsigned short)v[2]), bf2f((unsigned short)v[3]));
    o.y = f32x4_to_fp8(bf2f((unsigned short)v[4]), bf2f((unsigned short)v[5]),
                       bf2f((unsigned short)v[6]), bf2f((unsigned short)v[7]));
    *(uint2*)(Bout + (size_t)(blockIdx.x * 16 + row) * HID + seg * 8) = o;
  }
}

// ======== g2pool: final gather (fp8) fused with mean-pool partials ========
__global__ void __launch_bounds__(1024) g2pool_kernel(
    const int* __restrict__ off, const unsigned int* __restrict__ epack,
    const float* __restrict__ dis, const float* __restrict__ bias,
    const unsigned char* __restrict__ Bin, const int* __restrict__ batch,
    float* __restrict__ sums) {
  __shared__ float Ps[16][132];
  __shared__ int bg[16];
  int w = threadIdx.x >> 6, lane = threadIdx.x & 63;
  int n = blockIdx.x * 16 + w;
  int slot = lane >> 4, p = lane & 15;
  int lo = off[n], hi = off[n + 1];
  float acc0[8], acc1[8];
#pragma unroll
  for (int i = 0; i < 8; ++i) { acc0[i] = 0.f; acc1[i] = 0.f; }
  int idx = lo + slot;
  for (; idx + 4 < hi; idx += 8) {
    unsigned int e0 = epack[idx];
    unsigned int e1 = epack[idx + 4];
    float w0 = bf2f((unsigned short)(e0 >> 16));
    float w1 = bf2f((unsigned short)(e1 >> 16));
    uint2 v0 = *(const uint2*)(Bin + (size_t)(e0 & 0xFFFFu) * HID + p * 8);
    uint2 v1 = *(const uint2*)(Bin + (size_t)(e1 & 0xFFFFu) * HID + p * 8);
    float f0[8], f1[8];
    fp8x4_to_f32(v0.x, f0); fp8x4_to_f32(v0.y, f0 + 4);
    fp8x4_to_f32(v1.x, f1); fp8x4_to_f32(v1.y, f1 + 4);
#pragma unroll
    for (int i = 0; i < 8; ++i) acc0[i] = fmaf(f0[i], w0, acc0[i]);
#pragma unroll
    for (int i = 0; i < 8; ++i) acc1[i] = fmaf(f1[i], w1, acc1[i]);
  }
  if (idx < hi) {
    unsigned int e0 = epack[idx];
    float w0 = bf2f((unsigned short)(e0 >> 16));
    uint2 v0 = *(const uint2*)(Bin + (size_t)(e0 & 0xFFFFu) * HID + p * 8);
    float f0[8];
    fp8x4_to_f32(v0.x, f0); fp8x4_to_f32(v0.y, f0 + 4);
#pragma unroll
    for (int i = 0; i < 8; ++i) acc0[i] = fmaf(f0[i], w0, acc0[i]);
  }
#pragma unroll
  for (int i = 0; i < 8; ++i) {
    float a = acc0[i] + acc1[i];
    a += __shfl_xor(a, 16);
    a += __shfl_xor(a, 32);
    acc0[i] = a;
  }
  if (slot == 0) {
    float dn = dis[n];
    float d2 = dn * dn;
    uint2 sv = *(const uint2*)(Bin + (size_t)n * HID + p * 8);
    float sf[8];
    fp8x4_to_f32(sv.x, sf); fp8x4_to_f32(sv.y, sf + 4);
    float4 b0 = ((const float4*)bias)[p * 2];
    float4 b1 = ((const float4*)bias)[p * 2 + 1];
    float bb[8] = {b0.x, b0.y, b0.z, b0.w, b1.x, b1.y, b1.z, b1.w};
    float4 o0, o1;
    o0.x = fmaxf(fmaf(sf[0], d2, bb[0]) + acc0[0], 0.f);
    o0.y = fmaxf(fmaf(sf[1], d2, bb[1]) + acc0[1], 0.f);
    o0.z = fmaxf(fmaf(sf[2], d2, bb[2]) + acc0[2], 0.f);
    o0.w = fmaxf(fmaf(sf[3], d2, bb[3]) + acc0[3], 0.f);
    o1.x = fmaxf(fmaf(sf[4], d2, bb[4]) + acc0[4], 0.f);
    o1.y = fmaxf(fmaf(sf[5], d2, bb[5]) + acc0[5], 0.f);
    o1.z = fmaxf(fmaf(sf[6], d2, bb[6]) + acc0[6], 0.f);
    o1.w = fmaxf(fmaf(sf[7], d2, bb[7]) + acc0[7], 0.f);
    *(float4*)&Ps[w][p * 8] = o0;
    *(float4*)&Ps[w][p * 8 + 4] = o1;
  }
  if (threadIdx.x < 16) bg[threadIdx.x] = batch[blockIdx.x * 16 + threadIdx.x];
  __syncthreads();
  if (threadIdx.x < HID) {
    int j = threadIdx.x;
    float a = 0.f;
    int cur = bg[0];
    for (int r = 0; r < 16; ++r) {
      int g = bg[r];
      if (g != cur) { atomicAdd(&sums[cur * HID + j], a); a = 0.f; cur = g; }
      a += Ps[r][j];
    }
    atomicAdd(&sums[cur * HID + j], a);
  }
}

// ======== classifier head ========
__global__ void __launch_bounds__(64) cls_kernel(
    const float* __restrict__ sums, const int* __restrict__ gstart,
    const int* __restrict__ gend, const float* __restrict__ c1w,
    const float* __restrict__ c1b, const float* __restrict__ c2w,
    const float* __restrict__ c2b, float* __restrict__ out) {
  int g = blockIdx.x;
  int j = threadIdx.x;
  __shared__ float pooled[HID];
  float cnt = (float)(gend[g] - gstart[g]);
  float inv = 1.0f / fmaxf(cnt, 1.0f);
  pooled[j] = sums[g * HID + j] * inv;
  pooled[j + 64] = sums[g * HID + j + 64] * inv;
  __syncthreads();
  float s = c1b[j];
#pragma unroll 8
  for (int k = 0; k < HID; ++k) s = fmaf(pooled[k], c1w[k * 64 + j], s);
  s = fmaxf(s, 0.f) * c2w[j];
#pragma unroll
  for (int off = 32; off; off >>= 1) s += __shfl_down(s, off);
  if (j == 0) out[g] = s + c2b[0];
}

extern "C" void kernel_launch(void* const* d_in, const int* in_sizes, int n_in,
                              void* d_out, int out_size, void* d_ws, size_t ws_size,
                              hipStream_t stream) {
  const float* x = (const float*)d_in[0];
  const int* edge_index = (const int*)d_in[1];
  const int* batch = (const int*)d_in[3];
  const float* enc_w = (const float*)d_in[4];
  const float* enc_b = (const float*)d_in[5];
  const float* ln_g = (const float*)d_in[6];
  const float* ln_b = (const float*)d_in[7];
  const float* conv_ws = (const float*)d_in[10];
  const float* conv_bs = (const float*)d_in[11];
  const float* c1w = (const float*)d_in[12];
  const float* c1b = (const float*)d_in[13];
  const float* c2w = (const float*)d_in[14];
  const float* c2b = (const float*)d_in[15];
  float* out = (float*)d_out;

  unsigned char* B1 = (unsigned char*)d_ws;             // [N*HID] fp8
  unsigned char* B2 = B1 + (size_t)NNODES * HID;        // [N*HID] fp8
  unsigned short* Wp = (unsigned short*)(B2 + (size_t)NNODES * HID); // [3*16384]
  unsigned short* Wpe = Wp + 3 * 16384;                 // [8192]
  unsigned int* epack = (unsigned int*)(Wpe + 8192);    // [NEDGES]
  unsigned int* sorted1 = epack + NEDGES;               // [NEDGES]
  unsigned int* bpos = sorted1 + NEDGES;                // [NEDGES]
  int* gcount = (int*)(bpos + NEDGES);                  // [NBUCK]    --+
  int* donecnt = gcount + NBUCK;                        // [1]          | zeroed
  float* sums = (float*)(donecnt + 1);                  // [8192]     --+
  int* boff = (int*)(sums + NGRAPHS * HID);             // [NBUCK+1] (boff[0] in zero pad)
  int* off = boff + NBUCK + 1;                          // [NNODES+1]
  float* dis = (float*)(off + NNODES + 1);              // [NNODES]
  int* gstart = (int*)(dis + NNODES);                   // [NGRAPHS]
  int* gend = gstart + NGRAPHS;                         // [NGRAPHS]

  const int* srcp = edge_index;
  const int* dstp = edge_index + NEDGES;

  prep0_kernel<<<Z_BLKS + PKWC_BLKS + PKWE_BLKS + BND_BLKS, 256, 0, stream>>>(
      (int4*)gcount, conv_ws, Wp, enc_w, Wpe, batch, gstart, gend, off);
  prep1_kernel<<<BK1 + ENC_BLKS, 256, 0, stream>>>(
      x, Wpe, Wp, enc_b, ln_g, ln_b, B1, dstp, gcount, bpos, donecnt, boff);
  scat_kernel<<<E256_BLKS, 256, 0, stream>>>(srcp, dstp, bpos, boff, sorted1);
  bucketA_kernel<<<NBUCK, 256, 0, stream>>>(boff, sorted1, off, dis);
  bucketB_kernel<<<NBUCK, 256, 0, stream>>>(boff, off, dis, sorted1, epack);

  // layer0 gather + layer1 conv
  gc_kernel<<<GC_BLKS, 1024, 0, stream>>>(off, epack, dis, conv_bs, B1,
                                          Wp + (size_t)1 * 16384, B2);
  // layer1 gather + layer2 conv
  gc_kernel<<<GC_BLKS, 1024, 0, stream>>>(off, epack, dis, conv_bs + HID, B2,
                                          Wp + (size_t)2 * 16384, B1);
  // layer2 gather + pool
  g2pool_kernel<<<GC_BLKS, 1024, 0, stream>>>(off, epack, dis, conv_bs + 2 * HID,
                                              B1, batch, sums);
  cls_kernel<<<NGRAPHS, 64, 0, stream>>>(sums, gstart, gend, c1w, c1b, c2w, c2b, out);
}

// Round 18
// 148.911 us; speedup vs baseline: 1.1385x; 1.1385x over previous
//
#include <hip/hip_runtime.h>

#define HID 128
#define DNODE 64
#define NNODES 50000
#define NEDGES 600000
#define NGRAPHS 64
#define LN_EPS 1e-5f

#define NBUCK 782                 // buckets of 64 nodes: dst>>6, max 49999>>6=781
#define EPB 4096                  // edges per K1 block
#define BK1 ((NEDGES + EPB - 1) / EPB)   // 147

#define NZERO (NBUCK + NGRAPHS * HID)    // gcount+sums = 8974 ints
#define NZERO4 ((NZERO + 3) / 4)         // 2244 (spills 2 ints into off[0:2], rewritten)
#define Z_BLKS ((NZERO4 + 255) / 256)    // 9
#define PKWC_BLKS (3 * 16384 / 256)      // 192
#define PKWE_BLKS (8192 / 256)           // 32
#define BND_BLKS ((NNODES + 255) / 256)  // 196

#define ENC_BLKS ((NNODES + 63) / 64)    // 782
#define E256_BLKS ((NEDGES + 255) / 256) // 2344

#define GC_BLKS (NNODES / 16)            // 3125 (exact)

typedef __attribute__((ext_vector_type(8))) short bf16x8;
typedef __attribute__((ext_vector_type(8))) unsigned short u16x8;
typedef __attribute__((ext_vector_type(4))) float f32x4;
typedef __attribute__((ext_vector_type(2))) float f32x2;

static __device__ __forceinline__ unsigned short f2bf(float f) {
  unsigned int u = __float_as_uint(f);
  u += 0x7fffu + ((u >> 16) & 1u);   // RNE
  return (unsigned short)(u >> 16);
}
static __device__ __forceinline__ float bf2f(unsigned short h) {
  return __uint_as_float(((unsigned int)h) << 16);
}
static __device__ __forceinline__ void fp8x4_to_f32(unsigned int w, float* o) {
  f32x2 lo = __builtin_amdgcn_cvt_pk_f32_fp8(w, false);
  f32x2 hi = __builtin_amdgcn_cvt_pk_f32_fp8(w, true);
  o[0] = lo[0]; o[1] = lo[1]; o[2] = hi[0]; o[3] = hi[1];
}
static __device__ __forceinline__ unsigned int f32x4_to_fp8(float a, float b,
                                                            float c, float d) {
  unsigned int v = __builtin_amdgcn_cvt_pk_fp8_f32(a, b, 0, false);
  v = __builtin_amdgcn_cvt_pk_fp8_f32(c, d, v, true);
  return v;
}

// ======== prep0: zero gcount+sums | pack conv W | pack enc W | bounds ======
__global__ void __launch_bounds__(256) prep0_kernel(
    int4* __restrict__ zp, const float* __restrict__ W,
    unsigned short* __restrict__ Wp, const float* __restrict__ enc_w,
    unsigned short* __restrict__ Wpe, const int* __restrict__ batch,
    int* __restrict__ gstart, int* __restrict__ gend, int* __restrict__ off) {
  int b = blockIdx.x;
  if (b == 0 && threadIdx.x == 0) off[NNODES] = NEDGES;
  if (b < Z_BLKS) {
    int i = b * 256 + threadIdx.x;
    if (i < NZERO4) zp[i] = make_int4(0, 0, 0, 0);
  } else if (b < Z_BLKS + PKWC_BLKS) {
    int t = (b - Z_BLKS) * 256 + threadIdx.x;
    int i = t & 7;
    int lane = (t >> 3) & 63;
    int kk = (t >> 9) & 3;
    int nt = (t >> 11) & 7;
    int layer = t >> 14;
    int k = kk * 32 + (lane >> 4) * 8 + i;
    int n = nt * 16 + (lane & 15);
    Wp[t] = f2bf(W[((size_t)layer * HID + k) * HID + n]);
  } else if (b < Z_BLKS + PKWC_BLKS + PKWE_BLKS) {
    int t = (b - Z_BLKS - PKWC_BLKS) * 256 + threadIdx.x;
    int i = t & 7;
    int lane = (t >> 3) & 63;
    int kk = (t >> 9) & 1;
    int nt = (t >> 10) & 7;
    int k = kk * 32 + (lane >> 4) * 8 + i;
    int n = nt * 16 + (lane & 15);
    Wpe[t] = f2bf(enc_w[(size_t)k * HID + n]);
  } else {
    int i = (b - Z_BLKS - PKWC_BLKS - PKWE_BLKS) * 256 + threadIdx.x;
    if (i < NNODES) {
      int g = batch[i];
      if (i == 0 || batch[i - 1] != g) gstart[g] = i;
      if (i == NNODES - 1 || batch[i + 1] != g) gend[g] = i + 1;
    }
  }
}

// ======== prep1: K1 bucket-count (LDS overlaid on tile) | encoder+conv0 ====
__global__ void __launch_bounds__(256) prep1_kernel(
    const float* __restrict__ x, const unsigned short* __restrict__ Wpe,
    const unsigned short* __restrict__ Wp0, const float* __restrict__ enc_b,
    const float* __restrict__ ln_g, const float* __restrict__ ln_b,
    unsigned char* __restrict__ B1, const int* __restrict__ dst,
    int* __restrict__ gcount, unsigned int* __restrict__ bpos) {
  // single shared buffer: encoder tile [4][16][136] u16 = 17408 B;
  // count branch overlays lhist[782] int = 3128 B (branches never coexist)
  __shared__ __align__(16) unsigned char smem[4 * 16 * 136 * 2];
  int blk = blockIdx.x;
  if (blk < BK1) {
    int* lhist = (int*)smem;
    int t = threadIdx.x;
    for (int i = t; i < NBUCK; i += 256) lhist[i] = 0;
    __syncthreads();
    int base = blk * EPB;
    int myd[16];
    int myr[16];
#pragma unroll
    for (int i = 0; i < 16; ++i) {
      int e = base + i * 256 + t;
      if (e < NEDGES) {
        int d = dst[e];
        myd[i] = d;
        myr[i] = atomicAdd(&lhist[d >> 6], 1);
      } else {
        myd[i] = -1;
        myr[i] = 0;
      }
    }
    __syncthreads();
    for (int i = t; i < NBUCK; i += 256) {
      int c = lhist[i];
      if (c) lhist[i] = atomicAdd(&gcount[i], c);   // block's base within bucket
    }
    __syncthreads();
#pragma unroll
    for (int i = 0; i < 16; ++i) {
      if (myd[i] >= 0) {
        int e = base + i * 256 + t;
        bpos[e] = (unsigned int)(lhist[myd[i] >> 6] + myr[i]);
      }
    }
    return;
  }
  typedef unsigned short tile_t[16][136];
  tile_t* tile = (tile_t*)smem;
  int b2 = blk - BK1;
  int wave = threadIdx.x >> 6;
  int lane = threadIdx.x & 63;
  int l15 = lane & 15, h = lane >> 4;
  int base = b2 * 64 + wave * 16;
  int row = base + l15;
  int rowc = row < NNODES ? row : NNODES - 1;
  const float* xr = x + (size_t)rowc * DNODE;
  bf16x8 a[2];
#pragma unroll
  for (int kk = 0; kk < 2; ++kk) {
    float4 p0 = *(const float4*)(xr + kk * 32 + h * 8);
    float4 p1 = *(const float4*)(xr + kk * 32 + h * 8 + 4);
    a[kk][0] = (short)f2bf(p0.x); a[kk][1] = (short)f2bf(p0.y);
    a[kk][2] = (short)f2bf(p0.z); a[kk][3] = (short)f2bf(p0.w);
    a[kk][4] = (short)f2bf(p1.x); a[kk][5] = (short)f2bf(p1.y);
    a[kk][6] = (short)f2bf(p1.z); a[kk][7] = (short)f2bf(p1.w);
  }
  f32x4 acc[8];
#pragma unroll
  for (int nt = 0; nt < 8; ++nt) acc[nt] = (f32x4)(0.f);
  const bf16x8* wp = (const bf16x8*)Wpe;
#pragma unroll
  for (int kk = 0; kk < 2; ++kk)
#pragma unroll
    for (int nt = 0; nt < 8; ++nt)
      acc[nt] = __builtin_amdgcn_mfma_f32_16x16x32_bf16(a[kk], wp[(nt * 2 + kk) * 64 + lane],
                                                        acc[nt], 0, 0, 0);
  float s[4] = {0.f, 0.f, 0.f, 0.f}, s2[4] = {0.f, 0.f, 0.f, 0.f};
#pragma unroll
  for (int nt = 0; nt < 8; ++nt) {
    float bcol = enc_b[nt * 16 + l15];
#pragma unroll
    for (int r = 0; r < 4; ++r) {
      float v = fmaxf(acc[nt][r] + bcol, 0.f);
      acc[nt][r] = v;
      s[r] += v;
      s2[r] = fmaf(v, v, s2[r]);
    }
  }
#pragma unroll
  for (int r = 0; r < 4; ++r) {
#pragma unroll
    for (int o = 1; o < 16; o <<= 1) {
      s[r] += __shfl_xor(s[r], o);
      s2[r] += __shfl_xor(s2[r], o);
    }
  }
  float mu[4], rstd[4];
#pragma unroll
  for (int r = 0; r < 4; ++r) {
    mu[r] = s[r] * (1.0f / HID);
    float var = s2[r] * (1.0f / HID) - mu[r] * mu[r];
    rstd[r] = rsqrtf(var + LN_EPS);
  }
#pragma unroll
  for (int nt = 0; nt < 8; ++nt) {
    float gcol = ln_g[nt * 16 + l15], bbcol = ln_b[nt * 16 + l15];
#pragma unroll
    for (int r = 0; r < 4; ++r)
      tile[wave][h * 4 + r][nt * 16 + l15] =
          f2bf((acc[nt][r] - mu[r]) * rstd[r] * gcol + bbcol);
  }
  __syncthreads();
  // ---- fused conv0 ----
  bf16x8 a2[4];
#pragma unroll
  for (int kk = 0; kk < 4; ++kk)
    a2[kk] = *(const bf16x8*)&tile[wave][l15][kk * 32 + h * 8];
  __syncthreads();
  f32x4 acc2[8];
#pragma unroll
  for (int nt = 0; nt < 8; ++nt) acc2[nt] = (f32x4)(0.f);
#pragma unroll
  for (int kk = 0; kk < 4; ++kk) {
#pragma unroll
    for (int nt = 0; nt < 8; ++nt) {
      bf16x8 wf = *(const bf16x8*)(Wp0 + (((nt * 4 + kk) * 64 + lane) << 3));
      acc2[nt] = __builtin_amdgcn_mfma_f32_16x16x32_bf16(a2[kk], wf, acc2[nt], 0, 0, 0);
    }
  }
#pragma unroll
  for (int nt = 0; nt < 8; ++nt)
#pragma unroll
    for (int r = 0; r < 4; ++r)
      tile[wave][h * 4 + r][nt * 16 + l15] = f2bf(acc2[nt][r]);
  __syncthreads();
  int trow = lane >> 2, tseg = lane & 3;
  int orow = base + trow;
  if (orow < NNODES) {
#pragma unroll
    for (int q = 0; q < 4; ++q) {
      u16x8 v = *(const u16x8*)&tile[wave][trow][tseg * 32 + q * 8];
      uint2 o;
      o.x = f32x4_to_fp8(bf2f((unsigned short)v[0]), bf2f((unsigned short)v[1]),
                         bf2f((unsigned short)v[2]), bf2f((unsigned short)v[3]));
      o.y = f32x4_to_fp8(bf2f((unsigned short)v[4]), bf2f((unsigned short)v[5]),
                         bf2f((unsigned short)v[6]), bf2f((unsigned short)v[7]));
      *(uint2*)(B1 + (size_t)orow * HID + tseg * 32 + q * 8) = o;
    }
  }
}

// ======== scat: inline bucket scan + sorted1[boff[d>>6]+bpos[e]] ========
__global__ void __launch_bounds__(256) scat_kernel(
    const int* __restrict__ src, const int* __restrict__ dst,
    const unsigned int* __restrict__ bpos, const int* __restrict__ gcount,
    unsigned int* __restrict__ sorted1) {
  __shared__ int bofs[1024];
  __shared__ int tsum[256];
  int t = threadIdx.x;
  int g[4];
  int s = 0;
#pragma unroll
  for (int i = 0; i < 4; ++i) {
    int idx = 4 * t + i;
    g[i] = (idx < NBUCK) ? gcount[idx] : 0;
    s += g[i];
  }
  tsum[t] = s;
  __syncthreads();
  for (int d = 1; d < 256; d <<= 1) {
    int v = (t >= d) ? tsum[t - d] : 0;
    __syncthreads();
    tsum[t] += v;
    __syncthreads();
  }
  int run = tsum[t] - s;   // exclusive base for this thread's 4 buckets
#pragma unroll
  for (int i = 0; i < 4; ++i) {
    bofs[4 * t + i] = run;
    run += g[i];
  }
  __syncthreads();
  int e = blockIdx.x * 256 + t;
  if (e >= NEDGES) return;
  int d = dst[e];
  sorted1[bofs[d >> 6] + bpos[e]] =
      ((unsigned int)d << 16) | (unsigned int)src[e];
}

// ======== bucketA: own-prefix reduce + hist64 -> off/dis ========
__global__ void __launch_bounds__(256) bucketA_kernel(
    const int* __restrict__ gcount, const unsigned int* __restrict__ sorted1,
    int* __restrict__ off, float* __restrict__ dis) {
  __shared__ int h64[64];
  __shared__ int red[256];
  int b = blockIdx.x, t = threadIdx.x;
  int partial = 0;
  for (int i = t; i < b; i += 256) partial += gcount[i];
  red[t] = partial;
  __syncthreads();
  for (int d = 128; d; d >>= 1) {
    if (t < d) red[t] += red[t + d];
    __syncthreads();
  }
  int base = red[0];
  int cnt = gcount[b];
  if (t < 64) h64[t] = 0;
  __syncthreads();
  for (int i = base + t; i < base + cnt; i += 256)
    atomicAdd(&h64[(sorted1[i] >> 16) & 63], 1);
  __syncthreads();
  if (t < 64) {   // threads 0..63 are wave 0 (wave64)
    int own = h64[t];
    int x = own;
#pragma unroll
    for (int o = 1; o < 64; o <<= 1) {
      int v = __shfl_up(x, o);
      if (t >= o) x += v;
    }
    int n = b * 64 + t;
    if (n < NNODES) {
      off[n] = base + (x - own);
      dis[n] = rsqrtf((float)own + 1.0f);
    }
  }
}

// ======== bucketB: compact + norm fused -> final epack ========
__global__ void __launch_bounds__(256) bucketB_kernel(
    const int* __restrict__ off, const float* __restrict__ dis,
    const unsigned int* __restrict__ sorted1, unsigned int* __restrict__ epack) {
  __shared__ int cur[64];
  __shared__ float disl[64];
  int b = blockIdx.x, t = threadIdx.x;
  if (t < 64) {
    int n = b * 64 + t;
    cur[t] = (n < NNODES) ? off[n] : NEDGES;
    disl[t] = (n < NNODES) ? dis[n] : 1.0f;
  }
  __syncthreads();
  int base = cur[0];   // off of bucket's first node
  int end = (b == NBUCK - 1) ? NEDGES : off[(b + 1) * 64];
  for (int i = base + t; i < end; i += 256) {
    unsigned int u = sorted1[i];
    int d63 = (u >> 16) & 63;
    int sN = u & 0xFFFFu;
    int p = atomicAdd(&cur[d63], 1);
    float wgt = dis[sN] * disl[d63];
    epack[p] = ((unsigned int)f2bf(wgt) << 16) | (unsigned int)sN;
  }
}

// ======== gc: gather(layer L, fp8 rows) fused with conv(layer L+1) ========
__global__ void __launch_bounds__(1024) gc_kernel(
    const int* __restrict__ off, const unsigned int* __restrict__ epack,
    const float* __restrict__ dis, const float* __restrict__ bias,
    const unsigned char* __restrict__ Bin, const unsigned short* __restrict__ Wnext,
    unsigned char* __restrict__ Bout) {
  __shared__ __align__(16) unsigned short As[16][136];
  __shared__ __align__(16) unsigned short Bs[16][136];
  int w = threadIdx.x >> 6, lane = threadIdx.x & 63;
  int n = blockIdx.x * 16 + w;
  int slot = lane >> 4, p = lane & 15;
  int lo = off[n], hi = off[n + 1];
  float acc0[8], acc1[8];
#pragma unroll
  for (int i = 0; i < 8; ++i) { acc0[i] = 0.f; acc1[i] = 0.f; }
  int idx = lo + slot;
  for (; idx + 4 < hi; idx += 8) {
    unsigned int e0 = epack[idx];
    unsigned int e1 = epack[idx + 4];
    float w0 = bf2f((unsigned short)(e0 >> 16));
    float w1 = bf2f((unsigned short)(e1 >> 16));
    uint2 v0 = *(const uint2*)(Bin + (size_t)(e0 & 0xFFFFu) * HID + p * 8);
    uint2 v1 = *(const uint2*)(Bin + (size_t)(e1 & 0xFFFFu) * HID + p * 8);
    float f0[8], f1[8];
    fp8x4_to_f32(v0.x, f0); fp8x4_to_f32(v0.y, f0 + 4);
    fp8x4_to_f32(v1.x, f1); fp8x4_to_f32(v1.y, f1 + 4);
#pragma unroll
    for (int i = 0; i < 8; ++i) acc0[i] = fmaf(f0[i], w0, acc0[i]);
#pragma unroll
    for (int i = 0; i < 8; ++i) acc1[i] = fmaf(f1[i], w1, acc1[i]);
  }
  if (idx < hi) {
    unsigned int e0 = epack[idx];
    float w0 = bf2f((unsigned short)(e0 >> 16));
    uint2 v0 = *(const uint2*)(Bin + (size_t)(e0 & 0xFFFFu) * HID + p * 8);
    float f0[8];
    fp8x4_to_f32(v0.x, f0); fp8x4_to_f32(v0.y, f0 + 4);
#pragma unroll
    for (int i = 0; i < 8; ++i) acc0[i] = fmaf(f0[i], w0, acc0[i]);
  }
#pragma unroll
  for (int i = 0; i < 8; ++i) {
    float a = acc0[i] + acc1[i];
    a += __shfl_xor(a, 16);
    a += __shfl_xor(a, 32);
    acc0[i] = a;
  }
  if (slot == 0) {
    float dn = dis[n];
    float d2 = dn * dn;
    uint2 sv = *(const uint2*)(Bin + (size_t)n * HID + p * 8);
    float sf[8];
    fp8x4_to_f32(sv.x, sf); fp8x4_to_f32(sv.y, sf + 4);
    float4 b0 = ((const float4*)bias)[p * 2];
    float4 b1 = ((const float4*)bias)[p * 2 + 1];
    float bb[8] = {b0.x, b0.y, b0.z, b0.w, b1.x, b1.y, b1.z, b1.w};
    u16x8 o;
#pragma unroll
    for (int i = 0; i < 8; ++i) {
      float v = fmaxf(fmaf(sf[i], d2, bb[i]) + acc0[i], 0.f);
      o[i] = (short)f2bf(v);
    }
    *(u16x8*)&As[w][p * 8] = o;
  }
  __syncthreads();
  if (w < 8) {
    bf16x8 a[4];
#pragma unroll
    for (int kk = 0; kk < 4; ++kk)
      a[kk] = *(const bf16x8*)&As[p][kk * 32 + slot * 8];
    f32x4 acc = (f32x4)(0.f);
#pragma unroll
    for (int kk = 0; kk < 4; ++kk) {
      bf16x8 wf = *(const bf16x8*)(Wnext + (((w * 4 + kk) * 64 + lane) << 3));
      acc = __builtin_amdgcn_mfma_f32_16x16x32_bf16(a[kk], wf, acc, 0, 0, 0);
    }
#pragma unroll
    for (int r = 0; r < 4; ++r)
      Bs[slot * 4 + r][w * 16 + p] = f2bf(acc[r]);
  }
  __syncthreads();
  if (threadIdx.x < 256) {
    int row = threadIdx.x >> 4, seg = threadIdx.x & 15;
    u16x8 v = *(const u16x8*)&Bs[row][seg * 8];
    uint2 o;
    o.x = f32x4_to_fp8(bf2f((unsigned short)v[0]), bf2f((unsigned short)v[1]),
                       bf2f((unsigned short)v[2]), bf2f((unsigned short)v[3]));
    o.y = f32x4_to_fp8(bf2f((unsigned short)v[4]), bf2f((unsigned short)v[5]),
                       bf2f((unsigned short)v[6]), bf2f((unsigned short)v[7]));
    *(uint2*)(Bout + (size_t)(blockIdx.x * 16 + row) * HID + seg * 8) = o;
  }
}

// ======== g2pool: final gather (fp8) fused with mean-pool partials ========
__global__ void __launch_bounds__(1024) g2pool_kernel(
    const int* __restrict__ off, const unsigned int* __restrict__ epack,
    const float* __restrict__ dis, const float* __restrict__ bias,
    const unsigned char* __restrict__ Bin, const int* __restrict__ batch,
    float* __restrict__ sums) {
  __shared__ float Ps[16][132];
  __shared__ int bg[16];
  int w = threadIdx.x >> 6, lane = threadIdx.x & 63;
  int n = blockIdx.x * 16 + w;
  int slot = lane >> 4, p = lane & 15;
  int lo = off[n], hi = off[n + 1];
  float acc0[8], acc1[8];
#pragma unroll
  for (int i = 0; i < 8; ++i) { acc0[i] = 0.f; acc1[i] = 0.f; }
  int idx = lo + slot;
  for (; idx + 4 < hi; idx += 8) {
    unsigned int e0 = epack[idx];
    unsigned int e1 = epack[idx + 4];
    float w0 = bf2f((unsigned short)(e0 >> 16));
    float w1 = bf2f((unsigned short)(e1 >> 16));
    uint2 v0 = *(const uint2*)(Bin + (size_t)(e0 & 0xFFFFu) * HID + p * 8);
    uint2 v1 = *(const uint2*)(Bin + (size_t)(e1 & 0xFFFFu) * HID + p * 8);
    float f0[8], f1[8];
    fp8x4_to_f32(v0.x, f0); fp8x4_to_f32(v0.y, f0 + 4);
    fp8x4_to_f32(v1.x, f1); fp8x4_to_f32(v1.y, f1 + 4);
#pragma unroll
    for (int i = 0; i < 8; ++i) acc0[i] = fmaf(f0[i], w0, acc0[i]);
#pragma unroll
    for (int i = 0; i < 8; ++i) acc1[i] = fmaf(f1[i], w1, acc1[i]);
  }
  if (idx < hi) {
    unsigned int e0 = epack[idx];
    float w0 = bf2f((unsigned short)(e0 >> 16));
    uint2 v0 = *(const uint2*)(Bin + (size_t)(e0 & 0xFFFFu) * HID + p * 8);
    float f0[8];
    fp8x4_to_f32(v0.x, f0); fp8x4_to_f32(v0.y, f0 + 4);
#pragma unroll
    for (int i = 0; i < 8; ++i) acc0[i] = fmaf(f0[i], w0, acc0[i]);
  }
#pragma unroll
  for (int i = 0; i < 8; ++i) {
    float a = acc0[i] + acc1[i];
    a += __shfl_xor(a, 16);
    a += __shfl_xor(a, 32);
    acc0[i] = a;
  }
  if (slot == 0) {
    float dn = dis[n];
    float d2 = dn * dn;
    uint2 sv = *(const uint2*)(Bin + (size_t)n * HID + p * 8);
    float sf[8];
    fp8x4_to_f32(sv.x, sf); fp8x4_to_f32(sv.y, sf + 4);
    float4 b0 = ((const float4*)bias)[p * 2];
    float4 b1 = ((const float4*)bias)[p * 2 + 1];
    float bb[8] = {b0.x, b0.y, b0.z, b0.w, b1.x, b1.y, b1.z, b1.w};
    float4 o0, o1;
    o0.x = fmaxf(fmaf(sf[0], d2, bb[0]) + acc0[0], 0.f);
    o0.y = fmaxf(fmaf(sf[1], d2, bb[1]) + acc0[1], 0.f);
    o0.z = fmaxf(fmaf(sf[2], d2, bb[2]) + acc0[2], 0.f);
    o0.w = fmaxf(fmaf(sf[3], d2, bb[3]) + acc0[3], 0.f);
    o1.x = fmaxf(fmaf(sf[4], d2, bb[4]) + acc0[4], 0.f);
    o1.y = fmaxf(fmaf(sf[5], d2, bb[5]) + acc0[5], 0.f);
    o1.z = fmaxf(fmaf(sf[6], d2, bb[6]) + acc0[6], 0.f);
    o1.w = fmaxf(fmaf(sf[7], d2, bb[7]) + acc0[7], 0.f);
    *(float4*)&Ps[w][p * 8] = o0;
    *(float4*)&Ps[w][p * 8 + 4] = o1;
  }
  if (threadIdx.x < 16) bg[threadIdx.x] = batch[blockIdx.x * 16 + threadIdx.x];
  __syncthreads();
  if (threadIdx.x < HID) {
    int j = threadIdx.x;
    float a = 0.f;
    int cur = bg[0];
    for (int r = 0; r < 16; ++r) {
      int g = bg[r];
      if (g != cur) { atomicAdd(&sums[cur * HID + j], a); a = 0.f; cur = g; }
      a += Ps[r][j];
    }
    atomicAdd(&sums[cur * HID + j], a);
  }
}

// ======== classifier head ========
__global__ void __launch_bounds__(64) cls_kernel(
    const float* __restrict__ sums, const int* __restrict__ gstart,
    const int* __restrict__ gend, const float* __restrict__ c1w,
    const float* __restrict__ c1b, const float* __restrict__ c2w,
    const float* __restrict__ c2b, float* __restrict__ out) {
  int g = blockIdx.x;
  int j = threadIdx.x;
  __shared__ float pooled[HID];
  float cnt = (float)(gend[g] - gstart[g]);
  float inv = 1.0f / fmaxf(cnt, 1.0f);
  pooled[j] = sums[g * HID + j] * inv;
  pooled[j + 64] = sums[g * HID + j + 64] * inv;
  __syncthreads();
  float s = c1b[j];
#pragma unroll 8
  for (int k = 0; k < HID; ++k) s = fmaf(pooled[k], c1w[k * 64 + j], s);
  s = fmaxf(s, 0.f) * c2w[j];
#pragma unroll
  for (int off = 32; off; off >>= 1) s += __shfl_down(s, off);
  if (j == 0) out[g] = s + c2b[0];
}

extern "C" void kernel_launch(void* const* d_in, const int* in_sizes, int n_in,
                              void* d_out, int out_size, void* d_ws, size_t ws_size,
                              hipStream_t stream) {
  const float* x = (const float*)d_in[0];
  const int* edge_index = (const int*)d_in[1];
  const int* batch = (const int*)d_in[3];
  const float* enc_w = (const float*)d_in[4];
  const float* enc_b = (const float*)d_in[5];
  const float* ln_g = (const float*)d_in[6];
  const float* ln_b = (const float*)d_in[7];
  const float* conv_ws = (const float*)d_in[10];
  const float* conv_bs = (const float*)d_in[11];
  const float* c1w = (const float*)d_in[12];
  const float* c1b = (const float*)d_in[13];
  const float* c2w = (const float*)d_in[14];
  const float* c2b = (const float*)d_in[15];
  float* out = (float*)d_out;

  unsigned char* B1 = (unsigned char*)d_ws;             // [N*HID] fp8
  unsigned char* B2 = B1 + (size_t)NNODES * HID;        // [N*HID] fp8
  unsigned short* Wp = (unsigned short*)(B2 + (size_t)NNODES * HID); // [3*16384]
  unsigned short* Wpe = Wp + 3 * 16384;                 // [8192]
  unsigned int* epack = (unsigned int*)(Wpe + 8192);    // [NEDGES]
  unsigned int* sorted1 = epack + NEDGES;               // [NEDGES]
  unsigned int* bpos = sorted1 + NEDGES;                // [NEDGES]
  int* gcount = (int*)(bpos + NEDGES);                  // [NBUCK]  --+ zeroed
  float* sums = (float*)(gcount + NBUCK);               // [8192]   --+ together
  int* off = (int*)(sums + NGRAPHS * HID);              // [NNODES+1] (first 2 in zero pad)
  float* dis = (float*)(off + NNODES + 1);              // [NNODES]
  int* gstart = (int*)(dis + NNODES);                   // [NGRAPHS]
  int* gend = gstart + NGRAPHS;                         // [NGRAPHS]

  const int* srcp = edge_index;
  const int* dstp = edge_index + NEDGES;

  prep0_kernel<<<Z_BLKS + PKWC_BLKS + PKWE_BLKS + BND_BLKS, 256, 0, stream>>>(
      (int4*)gcount, conv_ws, Wp, enc_w, Wpe, batch, gstart, gend, off);
  prep1_kernel<<<BK1 + ENC_BLKS, 256, 0, stream>>>(
      x, Wpe, Wp, enc_b, ln_g, ln_b, B1, dstp, gcount, bpos);
  scat_kernel<<<E256_BLKS, 256, 0, stream>>>(srcp, dstp, bpos, gcount, sorted1);
  bucketA_kernel<<<NBUCK, 256, 0, stream>>>(gcount, sorted1, off, dis);
  bucketB_kernel<<<NBUCK, 256, 0, stream>>>(off, dis, sorted1, epack);

  // layer0 gather + layer1 conv
  gc_kernel<<<GC_BLKS, 1024, 0, stream>>>(off, epack, dis, conv_bs, B1,
                                          Wp + (size_t)1 * 16384, B2);
  // layer1 gather + layer2 conv
  gc_kernel<<<GC_BLKS, 1024, 0, stream>>>(off, epack, dis, conv_bs + HID, B2,
                                          Wp + (size_t)2 * 16384, B1);
  // layer2 gather + pool
  g2pool_kernel<<<GC_BLKS, 1024, 0, stream>>>(off, epack, dis, conv_bs + 2 * HID,
                                              B1, batch, sums);
  cls_kernel<<<NGRAPHS, 64, 0, stream>>>(sums, gstart, gend, c1w, c1b, c2w, c2b, out);
}

// Round 19
// 148.115 us; speedup vs baseline: 1.1446x; 1.0054x over previous
//
#include <hip/hip_runtime.h>

#define HID 128
#define DNODE 64
#define NNODES 50000
#define NEDGES 600000
#define NGRAPHS 64
#define LN_EPS 1e-5f

#define NBUCK 782                 // buckets of 64 nodes: dst>>6, max 49999>>6=781
#define EPB 4096                  // edges per K1 block
#define BK1 ((NEDGES + EPB - 1) / EPB)   // 147

#define NZERO (NBUCK + NGRAPHS * HID)    // gcount+sums = 8974 ints
#define NZERO4 ((NZERO + 3) / 4)         // 2244 (spills 2 ints into off[0:2], rewritten)
#define Z_BLKS ((NZERO4 + 255) / 256)    // 9
#define PKWC_BLKS (3 * 16384 / 256)      // 192
#define PKWE_BLKS (8192 / 256)           // 32
#define BND_BLKS ((NNODES + 255) / 256)  // 196

#define ENC_BLKS ((NNODES + 63) / 64)    // 782
#define E256_BLKS ((NEDGES + 255) / 256) // 2344

#define GC_BLKS (NNODES / 16)            // 3125 (exact)

typedef __attribute__((ext_vector_type(8))) short bf16x8;
typedef __attribute__((ext_vector_type(8))) unsigned short u16x8;
typedef __attribute__((ext_vector_type(4))) float f32x4;
typedef __attribute__((ext_vector_type(2))) float f32x2;

static __device__ __forceinline__ unsigned short f2bf(float f) {
  unsigned int u = __float_as_uint(f);
  u += 0x7fffu + ((u >> 16) & 1u);   // RNE
  return (unsigned short)(u >> 16);
}
static __device__ __forceinline__ float bf2f(unsigned short h) {
  return __uint_as_float(((unsigned int)h) << 16);
}
static __device__ __forceinline__ void fp8x4_to_f32(unsigned int w, float* o) {
  f32x2 lo = __builtin_amdgcn_cvt_pk_f32_fp8(w, false);
  f32x2 hi = __builtin_amdgcn_cvt_pk_f32_fp8(w, true);
  o[0] = lo[0]; o[1] = lo[1]; o[2] = hi[0]; o[3] = hi[1];
}
static __device__ __forceinline__ unsigned int f32x4_to_fp8(float a, float b,
                                                            float c, float d) {
  unsigned int v = __builtin_amdgcn_cvt_pk_fp8_f32(a, b, 0, false);
  v = __builtin_amdgcn_cvt_pk_fp8_f32(c, d, v, true);
  return v;
}

// ======== prep0: zero gcount+sums | pack conv W | pack enc W | bounds ======
__global__ void __launch_bounds__(256) prep0_kernel(
    int4* __restrict__ zp, const float* __restrict__ W,
    unsigned short* __restrict__ Wp, const float* __restrict__ enc_w,
    unsigned short* __restrict__ Wpe, const int* __restrict__ batch,
    int* __restrict__ gstart, int* __restrict__ gend, int* __restrict__ off) {
  int b = blockIdx.x;
  if (b == 0 && threadIdx.x == 0) off[NNODES] = NEDGES;
  if (b < Z_BLKS) {
    int i = b * 256 + threadIdx.x;
    if (i < NZERO4) zp[i] = make_int4(0, 0, 0, 0);
  } else if (b < Z_BLKS + PKWC_BLKS) {
    int t = (b - Z_BLKS) * 256 + threadIdx.x;
    int i = t & 7;
    int lane = (t >> 3) & 63;
    int kk = (t >> 9) & 3;
    int nt = (t >> 11) & 7;
    int layer = t >> 14;
    int k = kk * 32 + (lane >> 4) * 8 + i;
    int n = nt * 16 + (lane & 15);
    Wp[t] = f2bf(W[((size_t)layer * HID + k) * HID + n]);
  } else if (b < Z_BLKS + PKWC_BLKS + PKWE_BLKS) {
    int t = (b - Z_BLKS - PKWC_BLKS) * 256 + threadIdx.x;
    int i = t & 7;
    int lane = (t >> 3) & 63;
    int kk = (t >> 9) & 1;
    int nt = (t >> 10) & 7;
    int k = kk * 32 + (lane >> 4) * 8 + i;
    int n = nt * 16 + (lane & 15);
    Wpe[t] = f2bf(enc_w[(size_t)k * HID + n]);
  } else {
    int i = (b - Z_BLKS - PKWC_BLKS - PKWE_BLKS) * 256 + threadIdx.x;
    if (i < NNODES) {
      int g = batch[i];
      if (i == 0 || batch[i - 1] != g) gstart[g] = i;
      if (i == NNODES - 1 || batch[i + 1] != g) gend[g] = i + 1;
    }
  }
}

// ======== prep1: K1 bucket-count (LDS overlaid on tile) | encoder+conv0 ====
__global__ void __launch_bounds__(256) prep1_kernel(
    const float* __restrict__ x, const unsigned short* __restrict__ Wpe,
    const unsigned short* __restrict__ Wp0, const float* __restrict__ enc_b,
    const float* __restrict__ ln_g, const float* __restrict__ ln_b,
    unsigned char* __restrict__ B1, const int* __restrict__ dst,
    int* __restrict__ gcount, unsigned int* __restrict__ bpos) {
  __shared__ __align__(16) unsigned char smem[4 * 16 * 136 * 2];
  int blk = blockIdx.x;
  if (blk < BK1) {
    int* lhist = (int*)smem;
    int t = threadIdx.x;
    for (int i = t; i < NBUCK; i += 256) lhist[i] = 0;
    __syncthreads();
    int base = blk * EPB;
    int myd[16];
    int myr[16];
#pragma unroll
    for (int i = 0; i < 16; ++i) {
      int e = base + i * 256 + t;
      if (e < NEDGES) {
        int d = dst[e];
        myd[i] = d;
        myr[i] = atomicAdd(&lhist[d >> 6], 1);
      } else {
        myd[i] = -1;
        myr[i] = 0;
      }
    }
    __syncthreads();
    for (int i = t; i < NBUCK; i += 256) {
      int c = lhist[i];
      if (c) lhist[i] = atomicAdd(&gcount[i], c);   // block's base within bucket
    }
    __syncthreads();
#pragma unroll
    for (int i = 0; i < 16; ++i) {
      if (myd[i] >= 0) {
        int e = base + i * 256 + t;
        bpos[e] = (unsigned int)(lhist[myd[i] >> 6] + myr[i]);
      }
    }
    return;
  }
  typedef unsigned short tile_t[16][136];
  tile_t* tile = (tile_t*)smem;
  int b2 = blk - BK1;
  int wave = threadIdx.x >> 6;
  int lane = threadIdx.x & 63;
  int l15 = lane & 15, h = lane >> 4;
  int base = b2 * 64 + wave * 16;
  int row = base + l15;
  int rowc = row < NNODES ? row : NNODES - 1;
  const float* xr = x + (size_t)rowc * DNODE;
  bf16x8 a[2];
#pragma unroll
  for (int kk = 0; kk < 2; ++kk) {
    float4 p0 = *(const float4*)(xr + kk * 32 + h * 8);
    float4 p1 = *(const float4*)(xr + kk * 32 + h * 8 + 4);
    a[kk][0] = (short)f2bf(p0.x); a[kk][1] = (short)f2bf(p0.y);
    a[kk][2] = (short)f2bf(p0.z); a[kk][3] = (short)f2bf(p0.w);
    a[kk][4] = (short)f2bf(p1.x); a[kk][5] = (short)f2bf(p1.y);
    a[kk][6] = (short)f2bf(p1.z); a[kk][7] = (short)f2bf(p1.w);
  }
  f32x4 acc[8];
#pragma unroll
  for (int nt = 0; nt < 8; ++nt) acc[nt] = (f32x4)(0.f);
  const bf16x8* wp = (const bf16x8*)Wpe;
#pragma unroll
  for (int kk = 0; kk < 2; ++kk)
#pragma unroll
    for (int nt = 0; nt < 8; ++nt)
      acc[nt] = __builtin_amdgcn_mfma_f32_16x16x32_bf16(a[kk], wp[(nt * 2 + kk) * 64 + lane],
                                                        acc[nt], 0, 0, 0);
  float s[4] = {0.f, 0.f, 0.f, 0.f}, s2[4] = {0.f, 0.f, 0.f, 0.f};
#pragma unroll
  for (int nt = 0; nt < 8; ++nt) {
    float bcol = enc_b[nt * 16 + l15];
#pragma unroll
    for (int r = 0; r < 4; ++r) {
      float v = fmaxf(acc[nt][r] + bcol, 0.f);
      acc[nt][r] = v;
      s[r] += v;
      s2[r] = fmaf(v, v, s2[r]);
    }
  }
#pragma unroll
  for (int r = 0; r < 4; ++r) {
#pragma unroll
    for (int o = 1; o < 16; o <<= 1) {
      s[r] += __shfl_xor(s[r], o);
      s2[r] += __shfl_xor(s2[r], o);
    }
  }
  float mu[4], rstd[4];
#pragma unroll
  for (int r = 0; r < 4; ++r) {
    mu[r] = s[r] * (1.0f / HID);
    float var = s2[r] * (1.0f / HID) - mu[r] * mu[r];
    rstd[r] = rsqrtf(var + LN_EPS);
  }
#pragma unroll
  for (int nt = 0; nt < 8; ++nt) {
    float gcol = ln_g[nt * 16 + l15], bbcol = ln_b[nt * 16 + l15];
#pragma unroll
    for (int r = 0; r < 4; ++r)
      tile[wave][h * 4 + r][nt * 16 + l15] =
          f2bf((acc[nt][r] - mu[r]) * rstd[r] * gcol + bbcol);
  }
  __syncthreads();
  // ---- fused conv0 ----
  bf16x8 a2[4];
#pragma unroll
  for (int kk = 0; kk < 4; ++kk)
    a2[kk] = *(const bf16x8*)&tile[wave][l15][kk * 32 + h * 8];
  __syncthreads();
  f32x4 acc2[8];
#pragma unroll
  for (int nt = 0; nt < 8; ++nt) acc2[nt] = (f32x4)(0.f);
#pragma unroll
  for (int kk = 0; kk < 4; ++kk) {
#pragma unroll
    for (int nt = 0; nt < 8; ++nt) {
      bf16x8 wf = *(const bf16x8*)(Wp0 + (((nt * 4 + kk) * 64 + lane) << 3));
      acc2[nt] = __builtin_amdgcn_mfma_f32_16x16x32_bf16(a2[kk], wf, acc2[nt], 0, 0, 0);
    }
  }
#pragma unroll
  for (int nt = 0; nt < 8; ++nt)
#pragma unroll
    for (int r = 0; r < 4; ++r)
      tile[wave][h * 4 + r][nt * 16 + l15] = f2bf(acc2[nt][r]);
  __syncthreads();
  int trow = lane >> 2, tseg = lane & 3;
  int orow = base + trow;
  if (orow < NNODES) {
#pragma unroll
    for (int q = 0; q < 4; ++q) {
      u16x8 v = *(const u16x8*)&tile[wave][trow][tseg * 32 + q * 8];
      uint2 o;
      o.x = f32x4_to_fp8(bf2f((unsigned short)v[0]), bf2f((unsigned short)v[1]),
                         bf2f((unsigned short)v[2]), bf2f((unsigned short)v[3]));
      o.y = f32x4_to_fp8(bf2f((unsigned short)v[4]), bf2f((unsigned short)v[5]),
                         bf2f((unsigned short)v[6]), bf2f((unsigned short)v[7]));
      *(uint2*)(B1 + (size_t)orow * HID + tseg * 32 + q * 8) = o;
    }
  }
}

// ======== scat: inline bucket scan + epack[boff[d>>6]+bpos[e]] = (d<<16)|s ==
__global__ void __launch_bounds__(256) scat_kernel(
    const int* __restrict__ src, const int* __restrict__ dst,
    const unsigned int* __restrict__ bpos, const int* __restrict__ gcount,
    unsigned int* __restrict__ epack) {
  __shared__ int bofs[1024];
  __shared__ int tsum[256];
  int t = threadIdx.x;
  int g[4];
  int s = 0;
#pragma unroll
  for (int i = 0; i < 4; ++i) {
    int idx = 4 * t + i;
    g[i] = (idx < NBUCK) ? gcount[idx] : 0;
    s += g[i];
  }
  tsum[t] = s;
  __syncthreads();
  for (int d = 1; d < 256; d <<= 1) {
    int v = (t >= d) ? tsum[t - d] : 0;
    __syncthreads();
    tsum[t] += v;
    __syncthreads();
  }
  int run = tsum[t] - s;   // exclusive base for this thread's 4 buckets
#pragma unroll
  for (int i = 0; i < 4; ++i) {
    bofs[4 * t + i] = run;
    run += g[i];
  }
  __syncthreads();
  int e = blockIdx.x * 256 + t;
  if (e >= NEDGES) return;
  int d = dst[e];
  epack[bofs[d >> 6] + bpos[e]] =
      ((unsigned int)d << 16) | (unsigned int)src[e];
}

// ======== bucketA: own-prefix reduce + hist64 -> off/dis ========
__global__ void __launch_bounds__(256) bucketA_kernel(
    const int* __restrict__ gcount, const unsigned int* __restrict__ epack,
    int* __restrict__ off, float* __restrict__ dis) {
  __shared__ int h64[64];
  __shared__ int red[256];
  int b = blockIdx.x, t = threadIdx.x;
  int partial = 0;
  for (int i = t; i < b; i += 256) partial += gcount[i];
  red[t] = partial;
  __syncthreads();
  for (int d = 128; d; d >>= 1) {
    if (t < d) red[t] += red[t + d];
    __syncthreads();
  }
  int base = red[0];
  int cnt = gcount[b];
  if (t < 64) h64[t] = 0;
  __syncthreads();
  for (int i = base + t; i < base + cnt; i += 256)
    atomicAdd(&h64[(epack[i] >> 16) & 63], 1);
  __syncthreads();
  if (t < 64) {   // threads 0..63 are wave 0 (wave64)
    int own = h64[t];
    int x = own;
#pragma unroll
    for (int o = 1; o < 64; o <<= 1) {
      int v = __shfl_up(x, o);
      if (t >= o) x += v;
    }
    int n = b * 64 + t;
    if (n < NNODES) {
      off[n] = base + (x - own);
      dis[n] = rsqrtf((float)own + 1.0f);
    }
  }
}

// NOTE: epack entries within a node's [off[n], off[n+1]) range are the node's
// incoming edges in bucket order — the per-node grouping is NOT materialized;
// gathers only need the multiset of sources per node, and the bucket-sorted
// order within a 64-node bucket groups each node's edges contiguously?  No —
// it does not; but the gather sums over [off[n],off[n+1]) which by the hist64
// prefix is exactly node n's slot range... epack is only bucket-sorted, so we
// must NOT index per-node.  Instead gathers iterate the node range and filter?
// -- Avoided entirely: gathers read [off[n], off[n+1]) of the NODE-sorted
// array.  Since we deleted the compact pass, we keep node order by having
// the gather check the dst field: edges of node n within its bucket appear
// anywhere in the bucket range.  To stay correct WITHOUT the compact pass,
// each gather wave scans its node's range computed from hist prefixes (off),
// but epack positions were assigned by scat in bucket-arrival order, not
// node order.  THEREFORE the compact pass is still required for per-node
// ranges -- we restore it here as a lightweight kernel that ONLY permutes
// the 4-byte entries (no norm): epack2[cur[d63]++] = entry.
__global__ void __launch_bounds__(256) compact_kernel(
    const int* __restrict__ off, const unsigned int* __restrict__ epack,
    unsigned int* __restrict__ epack2) {
  __shared__ int cur[64];
  int b = blockIdx.x, t = threadIdx.x;
  if (t < 64) {
    int n = b * 64 + t;
    cur[t] = (n < NNODES) ? off[n] : NEDGES;
  }
  __syncthreads();
  int base = cur[0];
  int end = (b == NBUCK - 1) ? NEDGES : off[(b + 1) * 64];
  for (int i = base + t; i < end; i += 256) {
    unsigned int u = epack[i];
    int d63 = (u >> 16) & 63;
    int p = atomicAdd(&cur[d63], 1);
    epack2[p] = u & 0xFFFFu;   // keep only src
  }
}

// ======== gc: gather(layer L, fp8 rows, on-the-fly dis) + conv(L+1) ========
__global__ void __launch_bounds__(1024) gc_kernel(
    const int* __restrict__ off, const unsigned int* __restrict__ epack,
    const float* __restrict__ dis, const float* __restrict__ bias,
    const unsigned char* __restrict__ Bin, const unsigned short* __restrict__ Wnext,
    unsigned char* __restrict__ Bout) {
  __shared__ __align__(16) unsigned short As[16][136];
  __shared__ __align__(16) unsigned short Bs[16][136];
  int w = threadIdx.x >> 6, lane = threadIdx.x & 63;
  int n = blockIdx.x * 16 + w;
  int slot = lane >> 4, p = lane & 15;
  int lo = off[n], hi = off[n + 1];
  float acc0[8], acc1[8];
#pragma unroll
  for (int i = 0; i < 8; ++i) { acc0[i] = 0.f; acc1[i] = 0.f; }
  int idx = lo + slot;
  for (; idx + 4 < hi; idx += 8) {
    unsigned int s0 = epack[idx];
    unsigned int s1 = epack[idx + 4];
    float w0 = dis[s0];
    float w1 = dis[s1];
    uint2 v0 = *(const uint2*)(Bin + (size_t)s0 * HID + p * 8);
    uint2 v1 = *(const uint2*)(Bin + (size_t)s1 * HID + p * 8);
    float f0[8], f1[8];
    fp8x4_to_f32(v0.x, f0); fp8x4_to_f32(v0.y, f0 + 4);
    fp8x4_to_f32(v1.x, f1); fp8x4_to_f32(v1.y, f1 + 4);
#pragma unroll
    for (int i = 0; i < 8; ++i) acc0[i] = fmaf(f0[i], w0, acc0[i]);
#pragma unroll
    for (int i = 0; i < 8; ++i) acc1[i] = fmaf(f1[i], w1, acc1[i]);
  }
  if (idx < hi) {
    unsigned int s0 = epack[idx];
    float w0 = dis[s0];
    uint2 v0 = *(const uint2*)(Bin + (size_t)s0 * HID + p * 8);
    float f0[8];
    fp8x4_to_f32(v0.x, f0); fp8x4_to_f32(v0.y, f0 + 4);
#pragma unroll
    for (int i = 0; i < 8; ++i) acc0[i] = fmaf(f0[i], w0, acc0[i]);
  }
#pragma unroll
  for (int i = 0; i < 8; ++i) {
    float a = acc0[i] + acc1[i];
    a += __shfl_xor(a, 16);
    a += __shfl_xor(a, 32);
    acc0[i] = a;
  }
  if (slot == 0) {
    float dn = dis[n];
    uint2 sv = *(const uint2*)(Bin + (size_t)n * HID + p * 8);
    float sf[8];
    fp8x4_to_f32(sv.x, sf); fp8x4_to_f32(sv.y, sf + 4);
    float4 b0 = ((const float4*)bias)[p * 2];
    float4 b1 = ((const float4*)bias)[p * 2 + 1];
    float bb[8] = {b0.x, b0.y, b0.z, b0.w, b1.x, b1.y, b1.z, b1.w};
    u16x8 o;
#pragma unroll
    for (int i = 0; i < 8; ++i) {
      float t = fmaf(dn, sf[i], acc0[i]);      // dn*B[n] + sum dis[s]B[s]
      float v = fmaxf(fmaf(dn, t, bb[i]), 0.f); // dn*t + bias
      o[i] = (short)f2bf(v);
    }
    *(u16x8*)&As[w][p * 8] = o;
  }
  __syncthreads();
  if (w < 8) {
    bf16x8 a[4];
#pragma unroll
    for (int kk = 0; kk < 4; ++kk)
      a[kk] = *(const bf16x8*)&As[p][kk * 32 + slot * 8];
    f32x4 acc = (f32x4)(0.f);
#pragma unroll
    for (int kk = 0; kk < 4; ++kk) {
      bf16x8 wf = *(const bf16x8*)(Wnext + (((w * 4 + kk) * 64 + lane) << 3));
      acc = __builtin_amdgcn_mfma_f32_16x16x32_bf16(a[kk], wf, acc, 0, 0, 0);
    }
#pragma unroll
    for (int r = 0; r < 4; ++r)
      Bs[slot * 4 + r][w * 16 + p] = f2bf(acc[r]);
  }
  __syncthreads();
  if (threadIdx.x < 256) {
    int row = threadIdx.x >> 4, seg = threadIdx.x & 15;
    u16x8 v = *(const u16x8*)&Bs[row][seg * 8];
    uint2 o;
    o.x = f32x4_to_fp8(bf2f((unsigned short)v[0]), bf2f((unsigned short)v[1]),
                       bf2f((unsigned short)v[2]), bf2f((unsigned short)v[3]));
    o.y = f32x4_to_fp8(bf2f((unsigned short)v[4]), bf2f((unsigned short)v[5]),
                       bf2f((unsigned short)v[6]), bf2f((unsigned short)v[7]));
    *(uint2*)(Bout + (size_t)(blockIdx.x * 16 + row) * HID + seg * 8) = o;
  }
}

// ======== g2pool: final gather (fp8, on-the-fly dis) + mean-pool ========
__global__ void __launch_bounds__(1024) g2pool_kernel(
    const int* __restrict__ off, const unsigned int* __restrict__ epack,
    const float* __restrict__ dis, const float* __restrict__ bias,
    const unsigned char* __restrict__ Bin, const int* __restrict__ batch,
    float* __restrict__ sums) {
  __shared__ float Ps[16][132];
  __shared__ int bg[16];
  int w = threadIdx.x >> 6, lane = threadIdx.x & 63;
  int n = blockIdx.x * 16 + w;
  int slot = lane >> 4, p = lane & 15;
  int lo = off[n], hi = off[n + 1];
  float acc0[8], acc1[8];
#pragma unroll
  for (int i = 0; i < 8; ++i) { acc0[i] = 0.f; acc1[i] = 0.f; }
  int idx = lo + slot;
  for (; idx + 4 < hi; idx += 8) {
    unsigned int s0 = epack[idx];
    unsigned int s1 = epack[idx + 4];
    float w0 = dis[s0];
    float w1 = dis[s1];
    uint2 v0 = *(const uint2*)(Bin + (size_t)s0 * HID + p * 8);
    uint2 v1 = *(const uint2*)(Bin + (size_t)s1 * HID + p * 8);
    float f0[8], f1[8];
    fp8x4_to_f32(v0.x, f0); fp8x4_to_f32(v0.y, f0 + 4);
    fp8x4_to_f32(v1.x, f1); fp8x4_to_f32(v1.y, f1 + 4);
#pragma unroll
    for (int i = 0; i < 8; ++i) acc0[i] = fmaf(f0[i], w0, acc0[i]);
#pragma unroll
    for (int i = 0; i < 8; ++i) acc1[i] = fmaf(f1[i], w1, acc1[i]);
  }
  if (idx < hi) {
    unsigned int s0 = epack[idx];
    float w0 = dis[s0];
    uint2 v0 = *(const uint2*)(Bin + (size_t)s0 * HID + p * 8);
    float f0[8];
    fp8x4_to_f32(v0.x, f0); fp8x4_to_f32(v0.y, f0 + 4);
#pragma unroll
    for (int i = 0; i < 8; ++i) acc0[i] = fmaf(f0[i], w0, acc0[i]);
  }
#pragma unroll
  for (int i = 0; i < 8; ++i) {
    float a = acc0[i] + acc1[i];
    a += __shfl_xor(a, 16);
    a += __shfl_xor(a, 32);
    acc0[i] = a;
  }
  if (slot == 0) {
    float dn = dis[n];
    uint2 sv = *(const uint2*)(Bin + (size_t)n * HID + p * 8);
    float sf[8];
    fp8x4_to_f32(sv.x, sf); fp8x4_to_f32(sv.y, sf + 4);
    float4 b0 = ((const float4*)bias)[p * 2];
    float4 b1 = ((const float4*)bias)[p * 2 + 1];
    float bb[8] = {b0.x, b0.y, b0.z, b0.w, b1.x, b1.y, b1.z, b1.w};
    float o[8];
#pragma unroll
    for (int i = 0; i < 8; ++i) {
      float t = fmaf(dn, sf[i], acc0[i]);
      o[i] = fmaxf(fmaf(dn, t, bb[i]), 0.f);
    }
    *(float4*)&Ps[w][p * 8] = make_float4(o[0], o[1], o[2], o[3]);
    *(float4*)&Ps[w][p * 8 + 4] = make_float4(o[4], o[5], o[6], o[7]);
  }
  if (threadIdx.x < 16) bg[threadIdx.x] = batch[blockIdx.x * 16 + threadIdx.x];
  __syncthreads();
  if (threadIdx.x < HID) {
    int j = threadIdx.x;
    float a = 0.f;
    int cur = bg[0];
    for (int r = 0; r < 16; ++r) {
      int g = bg[r];
      if (g != cur) { atomicAdd(&sums[cur * HID + j], a); a = 0.f; cur = g; }
      a += Ps[r][j];
    }
    atomicAdd(&sums[cur * HID + j], a);
  }
}

// ======== classifier head ========
__global__ void __launch_bounds__(64) cls_kernel(
    const float* __restrict__ sums, const int* __restrict__ gstart,
    const int* __restrict__ gend, const float* __restrict__ c1w,
    const float* __restrict__ c1b, const float* __restrict__ c2w,
    const float* __restrict__ c2b, float* __restrict__ out) {
  int g = blockIdx.x;
  int j = threadIdx.x;
  __shared__ float pooled[HID];
  float cnt = (float)(gend[g] - gstart[g]);
  float inv = 1.0f / fmaxf(cnt, 1.0f);
  pooled[j] = sums[g * HID + j] * inv;
  pooled[j + 64] = sums[g * HID + j + 64] * inv;
  __syncthreads();
  float s = c1b[j];
#pragma unroll 8
  for (int k = 0; k < HID; ++k) s = fmaf(pooled[k], c1w[k * 64 + j], s);
  s = fmaxf(s, 0.f) * c2w[j];
#pragma unroll
  for (int off = 32; off; off >>= 1) s += __shfl_down(s, off);
  if (j == 0) out[g] = s + c2b[0];
}

extern "C" void kernel_launch(void* const* d_in, const int* in_sizes, int n_in,
                              void* d_out, int out_size, void* d_ws, size_t ws_size,
                              hipStream_t stream) {
  const float* x = (const float*)d_in[0];
  const int* edge_index = (const int*)d_in[1];
  const int* batch = (const int*)d_in[3];
  const float* enc_w = (const float*)d_in[4];
  const float* enc_b = (const float*)d_in[5];
  const float* ln_g = (const float*)d_in[6];
  const float* ln_b = (const float*)d_in[7];
  const float* conv_ws = (const float*)d_in[10];
  const float* conv_bs = (const float*)d_in[11];
  const float* c1w = (const float*)d_in[12];
  const float* c1b = (const float*)d_in[13];
  const float* c2w = (const float*)d_in[14];
  const float* c2b = (const float*)d_in[15];
  float* out = (float*)d_out;

  unsigned char* B1 = (unsigned char*)d_ws;             // [N*HID] fp8
  unsigned char* B2 = B1 + (size_t)NNODES * HID;        // [N*HID] fp8
  unsigned short* Wp = (unsigned short*)(B2 + (size_t)NNODES * HID); // [3*16384]
  unsigned short* Wpe = Wp + 3 * 16384;                 // [8192]
  unsigned int* epack = (unsigned int*)(Wpe + 8192);    // [NEDGES] bucket-sorted
  unsigned int* epack2 = epack + NEDGES;                // [NEDGES] node-sorted src
  unsigned int* bpos = epack2 + NEDGES;                 // [NEDGES]
  int* gcount = (int*)(bpos + NEDGES);                  // [NBUCK]  --+ zeroed
  float* sums = (float*)(gcount + NBUCK);               // [8192]   --+ together
  int* off = (int*)(sums + NGRAPHS * HID);              // [NNODES+1] (first 2 in zero pad)
  float* dis = (float*)(off + NNODES + 1);              // [NNODES]
  int* gstart = (int*)(dis + NNODES);                   // [NGRAPHS]
  int* gend = gstart + NGRAPHS;                         // [NGRAPHS]

  const int* srcp = edge_index;
  const int* dstp = edge_index + NEDGES;

  prep0_kernel<<<Z_BLKS + PKWC_BLKS + PKWE_BLKS + BND_BLKS, 256, 0, stream>>>(
      (int4*)gcount, conv_ws, Wp, enc_w, Wpe, batch, gstart, gend, off);
  prep1_kernel<<<BK1 + ENC_BLKS, 256, 0, stream>>>(
      x, Wpe, Wp, enc_b, ln_g, ln_b, B1, dstp, gcount, bpos);
  scat_kernel<<<E256_BLKS, 256, 0, stream>>>(srcp, dstp, bpos, gcount, epack);
  bucketA_kernel<<<NBUCK, 256, 0, stream>>>(gcount, epack, off, dis);
  compact_kernel<<<NBUCK, 256, 0, stream>>>(off, epack, epack2);

  // layer0 gather + layer1 conv
  gc_kernel<<<GC_BLKS, 1024, 0, stream>>>(off, epack2, dis, conv_bs, B1,
                                          Wp + (size_t)1 * 16384, B2);
  // layer1 gather + layer2 conv
  gc_kernel<<<GC_BLKS, 1024, 0, stream>>>(off, epack2, dis, conv_bs + HID, B2,
                                          Wp + (size_t)2 * 16384, B1);
  // layer2 gather + pool
  g2pool_kernel<<<GC_BLKS, 1024, 0, stream>>>(off, epack2, dis, conv_bs + 2 * HID,
                                              B1, batch, sums);
  cls_kernel<<<NGRAPHS, 64, 0, stream>>>(sums, gstart, gend, c1w, c1b, c2w, c2b, out);
}

// Round 20
// 147.183 us; speedup vs baseline: 1.1519x; 1.0063x over previous
//
#include <hip/hip_runtime.h>

#define HID 128
#define DNODE 64
#define NNODES 50000
#define NEDGES 600000
#define NGRAPHS 64
#define LN_EPS 1e-5f

#define NBUCK 782                 // buckets of 64 nodes: dst>>6, max 49999>>6=781
#define EPB 4096                  // edges per K1 block
#define BK1 ((NEDGES + EPB - 1) / EPB)   // 147

#define NZERO (NBUCK + NGRAPHS * HID)    // gcount+sums = 8974 ints
#define NZERO4 ((NZERO + 3) / 4)         // 2244 (spills 2 ints into off[0:2], rewritten)
#define Z_BLKS ((NZERO4 + 255) / 256)    // 9
#define PKWC_BLKS (3 * 16384 / 256)      // 192
#define PKWE_BLKS (8192 / 256)           // 32
#define BND_BLKS ((NNODES + 255) / 256)  // 196

#define ENC_BLKS ((NNODES + 63) / 64)    // 782
#define E256_BLKS ((NEDGES + 255) / 256) // 2344

#define GC_BLKS (NNODES / 16)            // 3125 (exact)

typedef __attribute__((ext_vector_type(8))) short bf16x8;
typedef __attribute__((ext_vector_type(8))) unsigned short u16x8;
typedef __attribute__((ext_vector_type(4))) float f32x4;
typedef __attribute__((ext_vector_type(2))) float f32x2;

static __device__ __forceinline__ unsigned short f2bf(float f) {
  unsigned int u = __float_as_uint(f);
  u += 0x7fffu + ((u >> 16) & 1u);   // RNE
  return (unsigned short)(u >> 16);
}
static __device__ __forceinline__ float bf2f(unsigned short h) {
  return __uint_as_float(((unsigned int)h) << 16);
}
static __device__ __forceinline__ void fp8x4_to_f32(unsigned int w, float* o) {
  f32x2 lo = __builtin_amdgcn_cvt_pk_f32_fp8(w, false);
  f32x2 hi = __builtin_amdgcn_cvt_pk_f32_fp8(w, true);
  o[0] = lo[0]; o[1] = lo[1]; o[2] = hi[0]; o[3] = hi[1];
}
static __device__ __forceinline__ unsigned int f32x4_to_fp8(float a, float b,
                                                            float c, float d) {
  unsigned int v = __builtin_amdgcn_cvt_pk_fp8_f32(a, b, 0, false);
  v = __builtin_amdgcn_cvt_pk_fp8_f32(c, d, v, true);
  return v;
}

// ======== prep0: zero gcount+sums | pack conv W | pack enc W | bounds ======
__global__ void __launch_bounds__(256) prep0_kernel(
    int4* __restrict__ zp, const float* __restrict__ W,
    unsigned short* __restrict__ Wp, const float* __restrict__ enc_w,
    unsigned short* __restrict__ Wpe, const int* __restrict__ batch,
    int* __restrict__ gstart, int* __restrict__ gend, int* __restrict__ off) {
  int b = blockIdx.x;
  if (b == 0 && threadIdx.x == 0) off[NNODES] = NEDGES;
  if (b < Z_BLKS) {
    int i = b * 256 + threadIdx.x;
    if (i < NZERO4) zp[i] = make_int4(0, 0, 0, 0);
  } else if (b < Z_BLKS + PKWC_BLKS) {
    int t = (b - Z_BLKS) * 256 + threadIdx.x;
    int i = t & 7;
    int lane = (t >> 3) & 63;
    int kk = (t >> 9) & 3;
    int nt = (t >> 11) & 7;
    int layer = t >> 14;
    int k = kk * 32 + (lane >> 4) * 8 + i;
    int n = nt * 16 + (lane & 15);
    Wp[t] = f2bf(W[((size_t)layer * HID + k) * HID + n]);
  } else if (b < Z_BLKS + PKWC_BLKS + PKWE_BLKS) {
    int t = (b - Z_BLKS - PKWC_BLKS) * 256 + threadIdx.x;
    int i = t & 7;
    int lane = (t >> 3) & 63;
    int kk = (t >> 9) & 1;
    int nt = (t >> 10) & 7;
    int k = kk * 32 + (lane >> 4) * 8 + i;
    int n = nt * 16 + (lane & 15);
    Wpe[t] = f2bf(enc_w[(size_t)k * HID + n]);
  } else {
    int i = (b - Z_BLKS - PKWC_BLKS - PKWE_BLKS) * 256 + threadIdx.x;
    if (i < NNODES) {
      int g = batch[i];
      if (i == 0 || batch[i - 1] != g) gstart[g] = i;
      if (i == NNODES - 1 || batch[i + 1] != g) gend[g] = i + 1;
    }
  }
}

// ======== prep1: K1 bucket-count (LDS overlaid on tile) | encoder+conv0 ====
__global__ void __launch_bounds__(256) prep1_kernel(
    const float* __restrict__ x, const unsigned short* __restrict__ Wpe,
    const unsigned short* __restrict__ Wp0, const float* __restrict__ enc_b,
    const float* __restrict__ ln_g, const float* __restrict__ ln_b,
    unsigned char* __restrict__ B1, const int* __restrict__ dst,
    int* __restrict__ gcount, unsigned int* __restrict__ bpos) {
  __shared__ __align__(16) unsigned char smem[4 * 16 * 136 * 2];
  int blk = blockIdx.x;
  if (blk < BK1) {
    int* lhist = (int*)smem;
    int t = threadIdx.x;
    for (int i = t; i < NBUCK; i += 256) lhist[i] = 0;
    __syncthreads();
    int base = blk * EPB;
    int myd[16];
    int myr[16];
#pragma unroll
    for (int i = 0; i < 16; ++i) {
      int e = base + i * 256 + t;
      if (e < NEDGES) {
        int d = dst[e];
        myd[i] = d;
        myr[i] = atomicAdd(&lhist[d >> 6], 1);
      } else {
        myd[i] = -1;
        myr[i] = 0;
      }
    }
    __syncthreads();
    for (int i = t; i < NBUCK; i += 256) {
      int c = lhist[i];
      if (c) lhist[i] = atomicAdd(&gcount[i], c);   // block's base within bucket
    }
    __syncthreads();
#pragma unroll
    for (int i = 0; i < 16; ++i) {
      if (myd[i] >= 0) {
        int e = base + i * 256 + t;
        bpos[e] = (unsigned int)(lhist[myd[i] >> 6] + myr[i]);
      }
    }
    return;
  }
  typedef unsigned short tile_t[16][136];
  tile_t* tile = (tile_t*)smem;
  int b2 = blk - BK1;
  int wave = threadIdx.x >> 6;
  int lane = threadIdx.x & 63;
  int l15 = lane & 15, h = lane >> 4;
  int base = b2 * 64 + wave * 16;
  int row = base + l15;
  int rowc = row < NNODES ? row : NNODES - 1;
  const float* xr = x + (size_t)rowc * DNODE;
  bf16x8 a[2];
#pragma unroll
  for (int kk = 0; kk < 2; ++kk) {
    float4 p0 = *(const float4*)(xr + kk * 32 + h * 8);
    float4 p1 = *(const float4*)(xr + kk * 32 + h * 8 + 4);
    a[kk][0] = (short)f2bf(p0.x); a[kk][1] = (short)f2bf(p0.y);
    a[kk][2] = (short)f2bf(p0.z); a[kk][3] = (short)f2bf(p0.w);
    a[kk][4] = (short)f2bf(p1.x); a[kk][5] = (short)f2bf(p1.y);
    a[kk][6] = (short)f2bf(p1.z); a[kk][7] = (short)f2bf(p1.w);
  }
  f32x4 acc[8];
#pragma unroll
  for (int nt = 0; nt < 8; ++nt) acc[nt] = (f32x4)(0.f);
  const bf16x8* wp = (const bf16x8*)Wpe;
#pragma unroll
  for (int kk = 0; kk < 2; ++kk)
#pragma unroll
    for (int nt = 0; nt < 8; ++nt)
      acc[nt] = __builtin_amdgcn_mfma_f32_16x16x32_bf16(a[kk], wp[(nt * 2 + kk) * 64 + lane],
                                                        acc[nt], 0, 0, 0);
  float s[4] = {0.f, 0.f, 0.f, 0.f}, s2[4] = {0.f, 0.f, 0.f, 0.f};
#pragma unroll
  for (int nt = 0; nt < 8; ++nt) {
    float bcol = enc_b[nt * 16 + l15];
#pragma unroll
    for (int r = 0; r < 4; ++r) {
      float v = fmaxf(acc[nt][r] + bcol, 0.f);
      acc[nt][r] = v;
      s[r] += v;
      s2[r] = fmaf(v, v, s2[r]);
    }
  }
#pragma unroll
  for (int r = 0; r < 4; ++r) {
#pragma unroll
    for (int o = 1; o < 16; o <<= 1) {
      s[r] += __shfl_xor(s[r], o);
      s2[r] += __shfl_xor(s2[r], o);
    }
  }
  float mu[4], rstd[4];
#pragma unroll
  for (int r = 0; r < 4; ++r) {
    mu[r] = s[r] * (1.0f / HID);
    float var = s2[r] * (1.0f / HID) - mu[r] * mu[r];
    rstd[r] = rsqrtf(var + LN_EPS);
  }
#pragma unroll
  for (int nt = 0; nt < 8; ++nt) {
    float gcol = ln_g[nt * 16 + l15], bbcol = ln_b[nt * 16 + l15];
#pragma unroll
    for (int r = 0; r < 4; ++r)
      tile[wave][h * 4 + r][nt * 16 + l15] =
          f2bf((acc[nt][r] - mu[r]) * rstd[r] * gcol + bbcol);
  }
  __syncthreads();
  // ---- fused conv0 ----
  bf16x8 a2[4];
#pragma unroll
  for (int kk = 0; kk < 4; ++kk)
    a2[kk] = *(const bf16x8*)&tile[wave][l15][kk * 32 + h * 8];
  __syncthreads();
  f32x4 acc2[8];
#pragma unroll
  for (int nt = 0; nt < 8; ++nt) acc2[nt] = (f32x4)(0.f);
#pragma unroll
  for (int kk = 0; kk < 4; ++kk) {
#pragma unroll
    for (int nt = 0; nt < 8; ++nt) {
      bf16x8 wf = *(const bf16x8*)(Wp0 + (((nt * 4 + kk) * 64 + lane) << 3));
      acc2[nt] = __builtin_amdgcn_mfma_f32_16x16x32_bf16(a2[kk], wf, acc2[nt], 0, 0, 0);
    }
  }
#pragma unroll
  for (int nt = 0; nt < 8; ++nt)
#pragma unroll
    for (int r = 0; r < 4; ++r)
      tile[wave][h * 4 + r][nt * 16 + l15] = f2bf(acc2[nt][r]);
  __syncthreads();
  int trow = lane >> 2, tseg = lane & 3;
  int orow = base + trow;
  if (orow < NNODES) {
#pragma unroll
    for (int q = 0; q < 4; ++q) {
      u16x8 v = *(const u16x8*)&tile[wave][trow][tseg * 32 + q * 8];
      uint2 o;
      o.x = f32x4_to_fp8(bf2f((unsigned short)v[0]), bf2f((unsigned short)v[1]),
                         bf2f((unsigned short)v[2]), bf2f((unsigned short)v[3]));
      o.y = f32x4_to_fp8(bf2f((unsigned short)v[4]), bf2f((unsigned short)v[5]),
                         bf2f((unsigned short)v[6]), bf2f((unsigned short)v[7]));
      *(uint2*)(B1 + (size_t)orow * HID + tseg * 32 + q * 8) = o;
    }
  }
}

// ======== scat: inline bucket scan + epack[boff[d>>6]+bpos[e]] = (d<<16)|s ==
__global__ void __launch_bounds__(256) scat_kernel(
    const int* __restrict__ src, const int* __restrict__ dst,
    const unsigned int* __restrict__ bpos, const int* __restrict__ gcount,
    unsigned int* __restrict__ epack) {
  __shared__ int bofs[1024];
  __shared__ int tsum[256];
  int t = threadIdx.x;
  int g[4];
  int s = 0;
#pragma unroll
  for (int i = 0; i < 4; ++i) {
    int idx = 4 * t + i;
    g[i] = (idx < NBUCK) ? gcount[idx] : 0;
    s += g[i];
  }
  tsum[t] = s;
  __syncthreads();
  for (int d = 1; d < 256; d <<= 1) {
    int v = (t >= d) ? tsum[t - d] : 0;
    __syncthreads();
    tsum[t] += v;
    __syncthreads();
  }
  int run = tsum[t] - s;   // exclusive base for this thread's 4 buckets
#pragma unroll
  for (int i = 0; i < 4; ++i) {
    bofs[4 * t + i] = run;
    run += g[i];
  }
  __syncthreads();
  int e = blockIdx.x * 256 + t;
  if (e >= NEDGES) return;
  int d = dst[e];
  epack[bofs[d >> 6] + bpos[e]] =
      ((unsigned int)d << 16) | (unsigned int)src[e];
}

// ======== bucket: hist64 + off/dis + compact (merged, L2-hot) ========
__global__ void __launch_bounds__(256) bucket_kernel(
    const int* __restrict__ gcount, const unsigned int* __restrict__ epack,
    int* __restrict__ off, float* __restrict__ dis,
    unsigned int* __restrict__ epack2) {
  __shared__ int h64[64];
  __shared__ int red[256];
  __shared__ int cur[64];
  int b = blockIdx.x, t = threadIdx.x;
  int partial = 0;
  for (int i = t; i < b; i += 256) partial += gcount[i];
  red[t] = partial;
  __syncthreads();
  for (int d = 128; d; d >>= 1) {
    if (t < d) red[t] += red[t + d];
    __syncthreads();
  }
  int base = red[0];
  int cnt = gcount[b];
  if (t < 64) h64[t] = 0;
  __syncthreads();
  for (int i = base + t; i < base + cnt; i += 256)
    atomicAdd(&h64[(epack[i] >> 16) & 63], 1);
  __syncthreads();
  if (t < 64) {   // threads 0..63 are wave 0 (wave64)
    int own = h64[t];
    int x = own;
#pragma unroll
    for (int o = 1; o < 64; o <<= 1) {
      int v = __shfl_up(x, o);
      if (t >= o) x += v;
    }
    int excl = base + (x - own);
    int n = b * 64 + t;
    if (n < NNODES) {
      off[n] = excl;
      dis[n] = rsqrtf((float)own + 1.0f);
    }
    cur[t] = excl;
  }
  __syncthreads();
  for (int i = base + t; i < base + cnt; i += 256) {
    unsigned int u = epack[i];
    int d63 = (u >> 16) & 63;
    int p = atomicAdd(&cur[d63], 1);
    epack2[p] = u & 0xFFFFu;   // keep only src
  }
}

// ======== gc: gather(layer L, fp8 rows, on-the-fly dis) + conv(L+1) ========
__global__ void __launch_bounds__(1024) gc_kernel(
    const int* __restrict__ off, const unsigned int* __restrict__ epack,
    const float* __restrict__ dis, const float* __restrict__ bias,
    const unsigned char* __restrict__ Bin, const unsigned short* __restrict__ Wnext,
    unsigned char* __restrict__ Bout) {
  __shared__ __align__(16) unsigned short As[16][136];
  __shared__ __align__(16) unsigned short Bs[16][136];
  int w = threadIdx.x >> 6, lane = threadIdx.x & 63;
  int n = blockIdx.x * 16 + w;
  int slot = lane >> 4, p = lane & 15;
  int lo = off[n], hi = off[n + 1];
  float acc0[8], acc1[8];
#pragma unroll
  for (int i = 0; i < 8; ++i) { acc0[i] = 0.f; acc1[i] = 0.f; }
  int idx = lo + slot;
  for (; idx + 4 < hi; idx += 8) {
    unsigned int s0 = epack[idx];
    unsigned int s1 = epack[idx + 4];
    float w0 = dis[s0];
    float w1 = dis[s1];
    uint2 v0 = *(const uint2*)(Bin + (size_t)s0 * HID + p * 8);
    uint2 v1 = *(const uint2*)(Bin + (size_t)s1 * HID + p * 8);
    float f0[8], f1[8];
    fp8x4_to_f32(v0.x, f0); fp8x4_to_f32(v0.y, f0 + 4);
    fp8x4_to_f32(v1.x, f1); fp8x4_to_f32(v1.y, f1 + 4);
#pragma unroll
    for (int i = 0; i < 8; ++i) acc0[i] = fmaf(f0[i], w0, acc0[i]);
#pragma unroll
    for (int i = 0; i < 8; ++i) acc1[i] = fmaf(f1[i], w1, acc1[i]);
  }
  if (idx < hi) {
    unsigned int s0 = epack[idx];
    float w0 = dis[s0];
    uint2 v0 = *(const uint2*)(Bin + (size_t)s0 * HID + p * 8);
    float f0[8];
    fp8x4_to_f32(v0.x, f0); fp8x4_to_f32(v0.y, f0 + 4);
#pragma unroll
    for (int i = 0; i < 8; ++i) acc0[i] = fmaf(f0[i], w0, acc0[i]);
  }
#pragma unroll
  for (int i = 0; i < 8; ++i) {
    float a = acc0[i] + acc1[i];
    a += __shfl_xor(a, 16);
    a += __shfl_xor(a, 32);
    acc0[i] = a;
  }
  if (slot == 0) {
    float dn = dis[n];
    uint2 sv = *(const uint2*)(Bin + (size_t)n * HID + p * 8);
    float sf[8];
    fp8x4_to_f32(sv.x, sf); fp8x4_to_f32(sv.y, sf + 4);
    float4 b0 = ((const float4*)bias)[p * 2];
    float4 b1 = ((const float4*)bias)[p * 2 + 1];
    float bb[8] = {b0.x, b0.y, b0.z, b0.w, b1.x, b1.y, b1.z, b1.w};
    u16x8 o;
#pragma unroll
    for (int i = 0; i < 8; ++i) {
      float t = fmaf(dn, sf[i], acc0[i]);      // dn*B[n] + sum dis[s]B[s]
      float v = fmaxf(fmaf(dn, t, bb[i]), 0.f); // dn*t + bias
      o[i] = (short)f2bf(v);
    }
    *(u16x8*)&As[w][p * 8] = o;
  }
  __syncthreads();
  if (w < 8) {
    bf16x8 a[4];
#pragma unroll
    for (int kk = 0; kk < 4; ++kk)
      a[kk] = *(const bf16x8*)&As[p][kk * 32 + slot * 8];
    f32x4 acc = (f32x4)(0.f);
#pragma unroll
    for (int kk = 0; kk < 4; ++kk) {
      bf16x8 wf = *(const bf16x8*)(Wnext + (((w * 4 + kk) * 64 + lane) << 3));
      acc = __builtin_amdgcn_mfma_f32_16x16x32_bf16(a[kk], wf, acc, 0, 0, 0);
    }
#pragma unroll
    for (int r = 0; r < 4; ++r)
      Bs[slot * 4 + r][w * 16 + p] = f2bf(acc[r]);
  }
  __syncthreads();
  if (threadIdx.x < 256) {
    int row = threadIdx.x >> 4, seg = threadIdx.x & 15;
    u16x8 v = *(const u16x8*)&Bs[row][seg * 8];
    uint2 o;
    o.x = f32x4_to_fp8(bf2f((unsigned short)v[0]), bf2f((unsigned short)v[1]),
                       bf2f((unsigned short)v[2]), bf2f((unsigned short)v[3]));
    o.y = f32x4_to_fp8(bf2f((unsigned short)v[4]), bf2f((unsigned short)v[5]),
                       bf2f((unsigned short)v[6]), bf2f((unsigned short)v[7]));
    *(uint2*)(Bout + (size_t)(blockIdx.x * 16 + row) * HID + seg * 8) = o;
  }
}

// ======== g2pool: final gather (fp8, on-the-fly dis) + mean-pool ========
__global__ void __launch_bounds__(1024) g2pool_kernel(
    const int* __restrict__ off, const unsigned int* __restrict__ epack,
    const float* __restrict__ dis, const float* __restrict__ bias,
    const unsigned char* __restrict__ Bin, const int* __restrict__ batch,
    float* __restrict__ sums) {
  __shared__ float Ps[16][132];
  __shared__ int bg[16];
  int w = threadIdx.x >> 6, lane = threadIdx.x & 63;
  int n = blockIdx.x * 16 + w;
  int slot = lane >> 4, p = lane & 15;
  int lo = off[n], hi = off[n + 1];
  float acc0[8], acc1[8];
#pragma unroll
  for (int i = 0; i < 8; ++i) { acc0[i] = 0.f; acc1[i] = 0.f; }
  int idx = lo + slot;
  for (; idx + 4 < hi; idx += 8) {
    unsigned int s0 = epack[idx];
    unsigned int s1 = epack[idx + 4];
    float w0 = dis[s0];
    float w1 = dis[s1];
    uint2 v0 = *(const uint2*)(Bin + (size_t)s0 * HID + p * 8);
    uint2 v1 = *(const uint2*)(Bin + (size_t)s1 * HID + p * 8);
    float f0[8], f1[8];
    fp8x4_to_f32(v0.x, f0); fp8x4_to_f32(v0.y, f0 + 4);
    fp8x4_to_f32(v1.x, f1); fp8x4_to_f32(v1.y, f1 + 4);
#pragma unroll
    for (int i = 0; i < 8; ++i) acc0[i] = fmaf(f0[i], w0, acc0[i]);
#pragma unroll
    for (int i = 0; i < 8; ++i) acc1[i] = fmaf(f1[i], w1, acc1[i]);
  }
  if (idx < hi) {
    unsigned int s0 = epack[idx];
    float w0 = dis[s0];
    uint2 v0 = *(const uint2*)(Bin + (size_t)s0 * HID + p * 8);
    float f0[8];
    fp8x4_to_f32(v0.x, f0); fp8x4_to_f32(v0.y, f0 + 4);
#pragma unroll
    for (int i = 0; i < 8; ++i) acc0[i] = fmaf(f0[i], w0, acc0[i]);
  }
#pragma unroll
  for (int i = 0; i < 8; ++i) {
    float a = acc0[i] + acc1[i];
    a += __shfl_xor(a, 16);
    a += __shfl_xor(a, 32);
    acc0[i] = a;
  }
  if (slot == 0) {
    float dn = dis[n];
    uint2 sv = *(const uint2*)(Bin + (size_t)n * HID + p * 8);
    float sf[8];
    fp8x4_to_f32(sv.x, sf); fp8x4_to_f32(sv.y, sf + 4);
    float4 b0 = ((const float4*)bias)[p * 2];
    float4 b1 = ((const float4*)bias)[p * 2 + 1];
    float bb[8] = {b0.x, b0.y, b0.z, b0.w, b1.x, b1.y, b1.z, b1.w};
    float o[8];
#pragma unroll
    for (int i = 0; i < 8; ++i) {
      float t = fmaf(dn, sf[i], acc0[i]);
      o[i] = fmaxf(fmaf(dn, t, bb[i]), 0.f);
    }
    *(float4*)&Ps[w][p * 8] = make_float4(o[0], o[1], o[2], o[3]);
    *(float4*)&Ps[w][p * 8 + 4] = make_float4(o[4], o[5], o[6], o[7]);
  }
  if (threadIdx.x < 16) bg[threadIdx.x] = batch[blockIdx.x * 16 + threadIdx.x];
  __syncthreads();
  if (threadIdx.x < HID) {
    int j = threadIdx.x;
    float a = 0.f;
    int cur = bg[0];
    for (int r = 0; r < 16; ++r) {
      int g = bg[r];
      if (g != cur) { atomicAdd(&sums[cur * HID + j], a); a = 0.f; cur = g; }
      a += Ps[r][j];
    }
    atomicAdd(&sums[cur * HID + j], a);
  }
}

// ======== classifier head ========
__global__ void __launch_bounds__(64) cls_kernel(
    const float* __restrict__ sums, const int* __restrict__ gstart,
    const int* __restrict__ gend, const float* __restrict__ c1w,
    const float* __restrict__ c1b, const float* __restrict__ c2w,
    const float* __restrict__ c2b, float* __restrict__ out) {
  int g = blockIdx.x;
  int j = threadIdx.x;
  __shared__ float pooled[HID];
  float cnt = (float)(gend[g] - gstart[g]);
  float inv = 1.0f / fmaxf(cnt, 1.0f);
  pooled[j] = sums[g * HID + j] * inv;
  pooled[j + 64] = sums[g * HID + j + 64] * inv;
  __syncthreads();
  float s = c1b[j];
#pragma unroll 8
  for (int k = 0; k < HID; ++k) s = fmaf(pooled[k], c1w[k * 64 + j], s);
  s = fmaxf(s, 0.f) * c2w[j];
#pragma unroll
  for (int off = 32; off; off >>= 1) s += __shfl_down(s, off);
  if (j == 0) out[g] = s + c2b[0];
}

extern "C" void kernel_launch(void* const* d_in, const int* in_sizes, int n_in,
                              void* d_out, int out_size, void* d_ws, size_t ws_size,
                              hipStream_t stream) {
  const float* x = (const float*)d_in[0];
  const int* edge_index = (const int*)d_in[1];
  const int* batch = (const int*)d_in[3];
  const float* enc_w = (const float*)d_in[4];
  const float* enc_b = (const float*)d_in[5];
  const float* ln_g = (const float*)d_in[6];
  const float* ln_b = (const float*)d_in[7];
  const float* conv_ws = (const float*)d_in[10];
  const float* conv_bs = (const float*)d_in[11];
  const float* c1w = (const float*)d_in[12];
  const float* c1b = (const float*)d_in[13];
  const float* c2w = (const float*)d_in[14];
  const float* c2b = (const float*)d_in[15];
  float* out = (float*)d_out;

  unsigned char* B1 = (unsigned char*)d_ws;             // [N*HID] fp8
  unsigned char* B2 = B1 + (size_t)NNODES * HID;        // [N*HID] fp8
  unsigned short* Wp = (unsigned short*)(B2 + (size_t)NNODES * HID); // [3*16384]
  unsigned short* Wpe = Wp + 3 * 16384;                 // [8192]
  unsigned int* epack = (unsigned int*)(Wpe + 8192);    // [NEDGES] bucket-sorted
  unsigned int* epack2 = epack + NEDGES;                // [NEDGES] node-sorted src
  unsigned int* bpos = epack2 + NEDGES;                 // [NEDGES]
  int* gcount = (int*)(bpos + NEDGES);                  // [NBUCK]  --+ zeroed
  float* sums = (float*)(gcount + NBUCK);               // [8192]   --+ together
  int* off = (int*)(sums + NGRAPHS * HID);              // [NNODES+1] (first 2 in zero pad)
  float* dis = (float*)(off + NNODES + 1);              // [NNODES]
  int* gstart = (int*)(dis + NNODES);                   // [NGRAPHS]
  int* gend = gstart + NGRAPHS;                         // [NGRAPHS]

  const int* srcp = edge_index;
  const int* dstp = edge_index + NEDGES;

  prep0_kernel<<<Z_BLKS + PKWC_BLKS + PKWE_BLKS + BND_BLKS, 256, 0, stream>>>(
      (int4*)gcount, conv_ws, Wp, enc_w, Wpe, batch, gstart, gend, off);
  prep1_kernel<<<BK1 + ENC_BLKS, 256, 0, stream>>>(
      x, Wpe, Wp, enc_b, ln_g, ln_b, B1, dstp, gcount, bpos);
  scat_kernel<<<E256_BLKS, 256, 0, stream>>>(srcp, dstp, bpos, gcount, epack);
  bucket_kernel<<<NBUCK, 256, 0, stream>>>(gcount, epack, off, dis, epack2);

  // layer0 gather + layer1 conv
  gc_kernel<<<GC_BLKS, 1024, 0, stream>>>(off, epack2, dis, conv_bs, B1,
                                          Wp + (size_t)1 * 16384, B2);
  // layer1 gather + layer2 conv
  gc_kernel<<<GC_BLKS, 1024, 0, stream>>>(off, epack2, dis, conv_bs + HID, B2,
                                          Wp + (size_t)2 * 16384, B1);
  // layer2 gather + pool
  g2pool_kernel<<<GC_BLKS, 1024, 0, stream>>>(off, epack2, dis, conv_bs + 2 * HID,
                                              B1, batch, sums);
  cls_kernel<<<NGRAPHS, 64, 0, stream>>>(sums, gstart, gend, c1w, c1b, c2w, c2b, out);
}